// Round 2
// baseline (603.999 us; speedup 1.0000x reference)
//
#include <hip/hip_runtime.h>
#include <hip/hip_bf16.h>

// ---------------------------------------------------------------------------
// DualRelationsPropagation on MI355X (gfx950) — round 2
// Changes vs r1: (1) fused relations kernel (div GEMM + sim + softmax +
// symmetrize + C), persistent |x_i-x_j| A-tile in LDS, no atomics/memset;
// (2) gemm_relT fuses rel_w f32->bf16 into the T GEMM (rel_w read once).
// ---------------------------------------------------------------------------

typedef __attribute__((ext_vector_type(8))) short s16x8;
typedef __attribute__((ext_vector_type(4))) float f32x4;

__device__ __forceinline__ short f2bf_s(float f){
  union { __hip_bfloat16 h; short s; } u; u.h = __float2bfloat16(f); return u.s;
}
__device__ __forceinline__ float bf_s2f(short s){
  union { __hip_bfloat16 h; short s; } u; u.s = s; return __bfloat162float(u.h);
}
__device__ __forceinline__ f32x4 mfma16(s16x8 a, s16x8 b, f32x4 c){
  return __builtin_amdgcn_mfma_f32_16x16x32_bf16(a, b, c, 0, 0, 0);
}

// async global->LDS, 16B per lane. LDS dest is wave-uniform base + lane*16
// (HW-implicit); global src is per-lane (pre-swizzle the SOURCE, rule 21).
__device__ __forceinline__ void gload16(void* lds, const void* g){
  __builtin_amdgcn_global_load_lds((const __attribute__((address_space(1))) void*)g,
                                   (__attribute__((address_space(3))) void*)lds,
                                   16, 0, 0);
}

// Swizzled LDS byte address for row-stride-128B tiles ([rows][64] bf16).
// rowbytes is a multiple of 128 -> low 7 bits come from col only, so
// addr = row*R + ((col*2) ^ ((row&7)<<4)) is the involution on both sides.
__device__ __forceinline__ char* swz64(short* base, int row, int col){
  return (char*)base + row*128 + ((col*2) ^ ((row&7)<<4));
}

// ---------------------------------------------------------------------------
// Generic bf16 GEMM: C(MxN) = A(MxK) * B^T  (B stored N x K row-major).
// 256 thr = 4 waves 2x2; per-wave (BM/2)x(BN/2). Register-staged LDS.
// EPI: 0 = f32 out, 2 = relu(+bias) -> bf16, 3 = +bias -> f32
// ---------------------------------------------------------------------------
template<int BM, int BN, int EPI>
__global__ __launch_bounds__(256) void gemm_bt(
    const short* __restrict__ A, int lda,
    const short* __restrict__ B, int ldb,
    float* __restrict__ Cf, short* __restrict__ Cb, int ldc,
    const float* __restrict__ bias, int K, int NT)
{
  __shared__ short As[BM*64];
  __shared__ short Bs[BN*64];
  const int tid = threadIdx.x, lane = tid & 63, wid = tid >> 6;
  const int nt = blockIdx.x % NT, mt = blockIdx.x / NT;
  const int m0 = mt*BM, n0 = nt*BN;
  const int wm0 = (wid>>1)*(BM/2), wn0 = (wid&1)*(BN/2);
  f32x4 acc[BM/32][BN/32] = {};
  for (int k0 = 0; k0 < K; k0 += 64){
    #pragma unroll
    for (int rd = 0; rd < (BM*64)/2048; ++rd){
      int ei = rd*2048 + tid*8, row = ei>>6, col = ei&63;
      *(uint4*)swz64(As,row,col) = *(const uint4*)(A + (size_t)(m0+row)*lda + k0 + col);
    }
    #pragma unroll
    for (int rd = 0; rd < (BN*64)/2048; ++rd){
      int ei = rd*2048 + tid*8, row = ei>>6, col = ei&63;
      *(uint4*)swz64(Bs,row,col) = *(const uint4*)(B + (size_t)(n0+row)*ldb + k0 + col);
    }
    __syncthreads();
    #pragma unroll
    for (int kk = 0; kk < 2; ++kk){
      const int kc = kk*32 + (lane>>4)*8;
      s16x8 af[BM/32], bfv[BN/32];
      #pragma unroll
      for (int mi = 0; mi < BM/32; ++mi)
        af[mi] = *(const s16x8*)swz64(As, wm0 + mi*16 + (lane&15), kc);
      #pragma unroll
      for (int ni = 0; ni < BN/32; ++ni)
        bfv[ni] = *(const s16x8*)swz64(Bs, wn0 + ni*16 + (lane&15), kc);
      #pragma unroll
      for (int mi = 0; mi < BM/32; ++mi)
        #pragma unroll
        for (int ni = 0; ni < BN/32; ++ni)
          acc[mi][ni] = mfma16(af[mi], bfv[ni], acc[mi][ni]);
    }
    __syncthreads();
  }
  #pragma unroll
  for (int mi = 0; mi < BM/32; ++mi){
    #pragma unroll
    for (int ni = 0; ni < BN/32; ++ni){
      const int gcol = n0 + wn0 + ni*16 + (lane&15);
      float bv = (EPI != 0) ? bias[gcol] : 0.f;
      #pragma unroll
      for (int r = 0; r < 4; ++r){
        const int grow = m0 + wm0 + mi*16 + (lane>>4)*4 + r;
        float v = acc[mi][ni][r] + bv;
        if (EPI == 2) v = fmaxf(v, 0.f);
        if (EPI == 0 || EPI == 3) Cf[(size_t)grow*ldc + gcol] = v;
        else                      Cb[(size_t)grow*ldc + gcol] = f2bf_s(v);
      }
    }
  }
}

// ---------------------------------------------------------------------------
// msg GEMM: C(MxN) = A(MxK) * B(KxN), B natural K-major (T buffer as 4096x768).
// B staged transposed via scalar swizzled ds_write. Epilogue *scale -> bf16.
// ---------------------------------------------------------------------------
__global__ __launch_bounds__(256) void gemm_bn_msg(
    const short* __restrict__ A, int lda,
    const short* __restrict__ B, int ldb,
    short* __restrict__ Co, int ldc, int ccol0,
    int K, int NT, float scale)
{
  __shared__ short As[64*64];
  __shared__ short Bs[64*64];
  const int tid = threadIdx.x, lane = tid & 63, wid = tid >> 6;
  const int nt = blockIdx.x % NT, mt = blockIdx.x / NT;
  const int m0 = mt*64, n0 = nt*64;
  const int wm0 = (wid>>1)*32, wn0 = (wid&1)*32;
  f32x4 acc[2][2] = {};
  for (int k0 = 0; k0 < K; k0 += 64){
    #pragma unroll
    for (int rd = 0; rd < 2; ++rd){
      int ei = rd*2048 + tid*8, row = ei>>6, col = ei&63;
      *(uint4*)swz64(As,row,col) = *(const uint4*)(A + (size_t)(m0+row)*lda + k0 + col);
    }
    #pragma unroll
    for (int rd = 0; rd < 2; ++rd){
      int ei = rd*2048 + tid*8, kr = ei>>6, nc = ei&63;
      union { uint4 v; short s[8]; } u;
      u.v = *(const uint4*)(B + (size_t)(k0+kr)*ldb + n0 + nc);
      #pragma unroll
      for (int e = 0; e < 8; ++e)
        *(short*)((char*)Bs + (nc+e)*128 + ((kr*2) ^ (((nc+e)&7)<<4))) = u.s[e];
    }
    __syncthreads();
    #pragma unroll
    for (int kk = 0; kk < 2; ++kk){
      const int kc = kk*32 + (lane>>4)*8;
      s16x8 af[2], bfv[2];
      #pragma unroll
      for (int mi = 0; mi < 2; ++mi)
        af[mi] = *(const s16x8*)swz64(As, wm0 + mi*16 + (lane&15), kc);
      #pragma unroll
      for (int ni = 0; ni < 2; ++ni)
        bfv[ni] = *(const s16x8*)swz64(Bs, wn0 + ni*16 + (lane&15), kc);
      #pragma unroll
      for (int mi = 0; mi < 2; ++mi)
        #pragma unroll
        for (int ni = 0; ni < 2; ++ni)
          acc[mi][ni] = mfma16(af[mi], bfv[ni], acc[mi][ni]);
    }
    __syncthreads();
  }
  #pragma unroll
  for (int mi = 0; mi < 2; ++mi)
    #pragma unroll
    for (int ni = 0; ni < 2; ++ni){
      const int gcol = n0 + wn0 + ni*16 + (lane&15);
      #pragma unroll
      for (int r = 0; r < 4; ++r){
        const int grow = m0 + wm0 + mi*16 + (lane>>4)*4 + r;
        Co[(size_t)grow*ldc + ccol0 + gcol] = f2bf_s(acc[mi][ni][r] * scale);
      }
    }
}

// ---------------------------------------------------------------------------
// Fused relations kernel. Grid dim3(4,256): jt = blockIdx.x (64-row j-tile),
// i = blockIdx.y. Skip blocks entirely below the diagonal. 512 threads.
// Per block: A = |x_j - x_i| (64x768) built ONCE into persistent LDS;
// 3 n-chunks of 256: div GEMM (MFMA, B via global_load_lds) -> hid_div ->
// 16-wide logits MFMA (register-accumulated, wave=(rowblk,khalf)); same for
// sim from precomputed P. Epilogue: softmax both, symmetrize, write sim/div/C.
// ---------------------------------------------------------------------------
__global__ __launch_bounds__(512) void relfused(
    const short* __restrict__ xb,      // COMB, x in cols [0,768), stride 1536
    const short* __restrict__ wbdiv,   // 768x768 bf16 (B^T)
    const float* __restrict__ P,       // 256x2304: [pa_sim | pb_sim | pa_div]
    const float* __restrict__ b1d, const float* __restrict__ b1s,
    const short* __restrict__ w2d_g, const short* __restrict__ w2s_g, // 16x768 bf16
    const float* __restrict__ b2d, const float* __restrict__ b2s,
    float* __restrict__ simo, float* __restrict__ divo, short* __restrict__ CB)
{
  const int jt = blockIdx.x, i = blockIdx.y;
  const int j0 = jt*64;
  if (i > j0 + 63) return;

  __shared__ short As[64*768];     // 96 KiB, persistent |x_j - x_i|
  __shared__ short Bs[64*256];     // 32 KiB: B-tiles (256x64), then hid (64x256)
  __shared__ short w2dl[16*256];   // 8 KiB: w2_div chunk; later stash_d f32[2][64][16]
  __shared__ short w2sl[16*256];   // 8 KiB: w2_sim chunk; later stash_s
  __shared__ float pabd[256];
  __shared__ float pabs[256];

  const int tid = threadIdx.x, lane = tid & 63, wv = tid >> 6;
  const int wr = wv >> 2, wc = wv & 3;          // main GEMM: 2(j) x 4(n) waves
  const int rowblk = wv & 3, khalf = wv >> 2;   // 2nd GEMM: 4 rowblks x 2 khalves
  const int lswz = (lane & 7) << 4;

  // ---- build A = |x_j - x_i| (rows 1536B, swizzled) ----
  {
    const int row = tid >> 3, l8 = tid & 7;
    const short* xj = xb + (size_t)(j0+row)*1536;
    const short* xi = xb + (size_t)i*1536;
    #pragma unroll
    for (int c = 0; c < 12; ++c){
      const int col = l8*8 + c*64;
      union { uint4 v; short s[8]; } uj, ui, uo;
      uj.v = *(const uint4*)(xj + col);
      ui.v = *(const uint4*)(xi + col);
      #pragma unroll
      for (int e = 0; e < 8; ++e)
        uo.s[e] = f2bf_s(fabsf(bf_s2f(uj.s[e]) - bf_s2f(ui.s[e])));
      *(uint4*)((char*)As + row*1536 + ((col*2) ^ ((row&7)<<4))) = uo.v;
    }
  }

  // frag row byte-bases (rowbytes multiple of 128 -> swizzle = lane-based)
  int abase[2], bbase[4];
  #pragma unroll
  for (int mi = 0; mi < 2; ++mi) abase[mi] = (wr*32 + mi*16 + (lane&15))*1536;
  #pragma unroll
  for (int ni = 0; ni < 4; ++ni) bbase[ni] = (wc*64 + ni*16 + (lane&15))*128;
  const int kfrag = (lane>>4)*16;

  f32x4 acc2d = {0.f,0.f,0.f,0.f}, acc2s = {0.f,0.f,0.f,0.f};

  for (int nt = 0; nt < 3; ++nt){
    const int n0 = nt*256;
    // pa + b1 for row i
    if (tid < 256) pabd[tid] = P[(size_t)i*2304 + 1536 + n0 + tid] + b1d[n0+tid];
    else { const int t = tid-256; pabs[t] = P[(size_t)i*2304 + n0 + t] + b1s[n0+t]; }
    // stage w2 chunks (16 x 256 each, rows 512B, swizzled-source gld_lds)
    {
      const int d = wv*1024 + lane*16;
      const int rr = d>>9, c = d&511;
      const size_t so = (size_t)rr*1536 + (size_t)n0*2 + (c ^ ((rr&7)<<4));
      gload16((char*)w2dl + wv*1024, (const char*)w2d_g + so);
      gload16((char*)w2sl + wv*1024, (const char*)w2s_g + so);
    }

    // ---- div main GEMM: G(64 x 256) over K=768 ----
    f32x4 acc[2][4] = {};
    for (int k0 = 0; k0 < 768; k0 += 64){
      #pragma unroll
      for (int q = 0; q < 4; ++q){
        const int d = wv*4096 + q*1024 + lane*16;
        const int row = d>>7, c = d&127;
        gload16((char*)Bs + wv*4096 + q*1024,
                (const char*)wbdiv + (size_t)(n0+row)*1536 + (size_t)k0*2 + (c ^ ((row&7)<<4)));
      }
      __syncthreads();
      #pragma unroll
      for (int kk = 0; kk < 2; ++kk){
        const int ka = (k0*2 + kk*64 + kfrag) ^ lswz;
        const int kb = (kk*64 + kfrag) ^ lswz;
        s16x8 af[2], bfv[4];
        #pragma unroll
        for (int mi = 0; mi < 2; ++mi) af[mi] = *(const s16x8*)((char*)As + abase[mi] + ka);
        #pragma unroll
        for (int ni = 0; ni < 4; ++ni) bfv[ni] = *(const s16x8*)((char*)Bs + bbase[ni] + kb);
        #pragma unroll
        for (int mi = 0; mi < 2; ++mi)
          #pragma unroll
          for (int ni = 0; ni < 4; ++ni)
            acc[mi][ni] = mfma16(af[mi], bfv[ni], acc[mi][ni]);
      }
      __syncthreads();
    }

    // ---- hid_div = relu(G + pa_div + b1d) -> Bs as [64][256] (512B rows) ----
    #pragma unroll
    for (int mi = 0; mi < 2; ++mi)
      #pragma unroll
      for (int ni = 0; ni < 4; ++ni){
        const int coln = wc*64 + ni*16 + (lane&15);
        const float pv = pabd[coln];
        #pragma unroll
        for (int r = 0; r < 4; ++r){
          const int rowj = wr*32 + mi*16 + (lane>>4)*4 + r;
          *(short*)((char*)Bs + rowj*512 + ((coln*2) ^ ((rowj&7)<<4)))
            = f2bf_s(fmaxf(acc[mi][ni][r] + pv, 0.f));
        }
      }
    __syncthreads();

    // ---- div 2nd GEMM: logits chunk, wave (rowblk, khalf), K=256 ----
    {
      const int rowj = rowblk*16 + (lane&15);
      #pragma unroll
      for (int q = 0; q < 4; ++q){
        const int kc2 = (khalf*256 + q*64 + kfrag) ^ lswz;
        s16x8 a = *(const s16x8*)((char*)Bs + rowj*512 + kc2);
        s16x8 b = *(const s16x8*)((char*)w2dl + (lane&15)*512 + kc2);
        acc2d = mfma16(a, b, acc2d);
      }
    }
    __syncthreads();

    // ---- hid_sim = relu(pa_sim + pb_sim + b1s) -> Bs ----
    {
      const int row = tid>>3, c0 = (tid&7)*32;
      const float* pb = P + (size_t)(j0+row)*2304 + 768 + n0 + c0;
      #pragma unroll
      for (int cc = 0; cc < 32; cc += 8){
        float4 v0 = *(const float4*)(pb+cc), v1 = *(const float4*)(pb+cc+4);
        float vv[8] = {v0.x,v0.y,v0.z,v0.w,v1.x,v1.y,v1.z,v1.w};
        union { uint4 v; short s[8]; } uo;
        #pragma unroll
        for (int e = 0; e < 8; ++e)
          uo.s[e] = f2bf_s(fmaxf(vv[e] + pabs[c0+cc+e], 0.f));
        *(uint4*)((char*)Bs + row*512 + (((c0+cc)*2) ^ ((row&7)<<4))) = uo.v;
      }
    }
    __syncthreads();

    // ---- sim 2nd GEMM ----
    {
      const int rowj = rowblk*16 + (lane&15);
      #pragma unroll
      for (int q = 0; q < 4; ++q){
        const int kc2 = (khalf*256 + q*64 + kfrag) ^ lswz;
        s16x8 a = *(const s16x8*)((char*)Bs + rowj*512 + kc2);
        s16x8 b = *(const s16x8*)((char*)w2sl + (lane&15)*512 + kc2);
        acc2s = mfma16(a, b, acc2s);
      }
    }
    __syncthreads();   // Bs/w2 reused next nt
  }

  // ---- stash partial logits (f32) into w2 regions ----
  {
    float* std_ = (float*)w2dl;
    float* sts_ = (float*)w2sl;
    const int rj = rowblk*16 + (lane>>4)*4;
    #pragma unroll
    for (int r = 0; r < 4; ++r){
      std_[(khalf*64 + rj + r)*16 + (lane&15)] = acc2d[r];
      sts_[(khalf*64 + rj + r)*16 + (lane&15)] = acc2s[r];
    }
  }
  __syncthreads();

  // ---- softmax + symmetrize + outputs (one thread per j-row) ----
  if (tid < 64){
    const int j = j0 + tid;
    if (j >= i){
      const float* std_ = (const float*)w2dl;
      const float* sts_ = (const float*)w2sl;
      float sd[16], ss[16];
      if (j == i){
        #pragma unroll
        for (int r = 0; r < 16; ++r){ sd[r] = 0.f; ss[r] = 0.f; }
      } else {
        float mx = -1e30f, sum;
        #pragma unroll
        for (int r = 0; r < 16; ++r){
          sd[r] = std_[tid*16+r] + std_[(64+tid)*16+r] + b2d[r];
          mx = fmaxf(mx, sd[r]);
        }
        sum = 0.f;
        #pragma unroll
        for (int r = 0; r < 16; ++r){ sd[r] = expf(sd[r]-mx); sum += sd[r]; }
        sum = 1.f/sum;
        #pragma unroll
        for (int r = 0; r < 16; ++r) sd[r] *= sum;
        mx = -1e30f;
        #pragma unroll
        for (int r = 0; r < 16; ++r){
          ss[r] = sts_[tid*16+r] + sts_[(64+tid)*16+r] + b2s[r];
          mx = fmaxf(mx, ss[r]);
        }
        sum = 0.f;
        #pragma unroll
        for (int r = 0; r < 16; ++r){ ss[r] = expf(ss[r]-mx); sum += ss[r]; }
        sum = 1.f/sum;
        #pragma unroll
        for (int r = 0; r < 16; ++r) ss[r] *= sum;
      }
      const size_t pij = ((size_t)i*256 + j)*16, pji = ((size_t)j*256 + i)*16;
      #pragma unroll
      for (int r = 0; r < 16; ++r){
        divo[pij+r] = sd[r]; divo[pji+r] = sd[r];
        simo[pij+r] = ss[r]; simo[pji+r] = ss[r];
        const short cb = f2bf_s(0.5f*(sd[r]+ss[r]));
        CB[pij+r] = cb; CB[pji+r] = cb;
      }
    }
  }
}

// ---------------------------------------------------------------------------
// T GEMM with fused rel_w f32->bf16: T(256 x 12288) = x(256x768) @ rel_w^T.
// rel_w layer is already (12288 x 768) f32 row-major = perfect B^T layout.
// Full-M blocks (grid = 192 n-tiles of 64), 512 threads = 8 waves (4m x 2n).
// A staged via global_load_lds (COMB bf16); B f32->bf16 in registers.
// ---------------------------------------------------------------------------
__global__ __launch_bounds__(512) void gemm_relT(
    const short* __restrict__ A,     // COMB, lda=1536
    const float* __restrict__ Bf,    // 12288 x 768 f32
    short* __restrict__ T,           // 256 x 12288 bf16
    const float* __restrict__ bias)  // 12288
{
  __shared__ short As[256*64];   // 32 KiB
  __shared__ short Bs[64*64];    // 8 KiB
  const int tid = threadIdx.x, lane = tid & 63, wv = tid >> 6;
  const int n0 = blockIdx.x*64;
  const int wm = wv >> 1, wn = wv & 1;
  const int lswz = (lane & 7) << 4;
  const int kfrag = (lane>>4)*16;
  const int brow = tid >> 3, bc0 = (tid & 7)*8;
  int abase[4], bbase[2];
  #pragma unroll
  for (int mi = 0; mi < 4; ++mi) abase[mi] = (wm*64 + mi*16 + (lane&15))*128;
  #pragma unroll
  for (int ni = 0; ni < 2; ++ni) bbase[ni] = (wn*32 + ni*16 + (lane&15))*128;
  f32x4 acc[4][2] = {};
  for (int k0 = 0; k0 < 768; k0 += 64){
    #pragma unroll
    for (int q = 0; q < 4; ++q){
      const int d = wv*4096 + q*1024 + lane*16;
      const int row = d>>7, c = d&127;
      gload16((char*)As + wv*4096 + q*1024,
              (const char*)A + (size_t)row*3072 + (size_t)k0*2 + (c ^ ((row&7)<<4)));
    }
    {
      const float* bp = Bf + (size_t)(n0+brow)*768 + k0 + bc0;
      float4 v0 = *(const float4*)bp, v1 = *(const float4*)(bp+4);
      float vv[8] = {v0.x,v0.y,v0.z,v0.w,v1.x,v1.y,v1.z,v1.w};
      union { uint4 v; short s[8]; } uo;
      #pragma unroll
      for (int e = 0; e < 8; ++e) uo.s[e] = f2bf_s(vv[e]);
      *(uint4*)((char*)Bs + brow*128 + ((bc0*2) ^ ((brow&7)<<4))) = uo.v;
    }
    __syncthreads();
    #pragma unroll
    for (int kk = 0; kk < 2; ++kk){
      const int kb = (kk*64 + kfrag) ^ lswz;
      s16x8 af[4], bfv[2];
      #pragma unroll
      for (int mi = 0; mi < 4; ++mi) af[mi] = *(const s16x8*)((char*)As + abase[mi] + kb);
      #pragma unroll
      for (int ni = 0; ni < 2; ++ni) bfv[ni] = *(const s16x8*)((char*)Bs + bbase[ni] + kb);
      #pragma unroll
      for (int mi = 0; mi < 4; ++mi)
        #pragma unroll
        for (int ni = 0; ni < 2; ++ni)
          acc[mi][ni] = mfma16(af[mi], bfv[ni], acc[mi][ni]);
    }
    __syncthreads();
  }
  #pragma unroll
  for (int mi = 0; mi < 4; ++mi)
    #pragma unroll
    for (int ni = 0; ni < 2; ++ni){
      const int nn = n0 + wn*32 + ni*16 + (lane&15);
      const float bv = bias[nn];
      #pragma unroll
      for (int r = 0; r < 4; ++r){
        const int row = wm*64 + mi*16 + (lane>>4)*4 + r;
        T[(size_t)row*12288 + nn] = f2bf_s(acc[mi][ni][r] + bv);
      }
    }
}

// ---------------------------------------------------------------------------
// LayerNorm(y + x) -> x (f32), comb[:, :768] (bf16), optional d_out x
// ---------------------------------------------------------------------------
__global__ __launch_bounds__(256) void ln_kernel(
    const float* __restrict__ y, float* __restrict__ x, short* __restrict__ combx,
    const float* __restrict__ g, const float* __restrict__ b, float* __restrict__ xfinal)
{
  const int row = blockIdx.x, tid = threadIdx.x;
  float tv[3]; float s = 0.f, s2 = 0.f;
  #pragma unroll
  for (int c = 0; c < 3; ++c){
    const int idx = tid + c*256;
    const float v = y[row*768+idx] + x[row*768+idx];
    tv[c] = v; s += v; s2 += v*v;
  }
  #pragma unroll
  for (int off = 32; off > 0; off >>= 1){ s += __shfl_down(s, off); s2 += __shfl_down(s2, off); }
  __shared__ float red[8];
  const int wid = tid >> 6, lane = tid & 63;
  if (lane == 0){ red[wid] = s; red[wid+4] = s2; }
  __syncthreads();
  if (tid == 0){
    red[0] = red[0]+red[1]+red[2]+red[3];
    red[4] = red[4]+red[5]+red[6]+red[7];
  }
  __syncthreads();
  const float mu = red[0]*(1.f/768.f);
  const float var = red[4]*(1.f/768.f) - mu*mu;
  const float inv = rsqrtf(var + 1e-5f);
  #pragma unroll
  for (int c = 0; c < 3; ++c){
    const int idx = tid + c*256;
    const float v = (tv[c]-mu)*inv*g[idx] + b[idx];
    x[row*768+idx] = v;
    combx[(size_t)row*1536 + idx] = f2bf_s(v);
    if (xfinal) xfinal[row*768+idx] = v;
  }
}

// ---------------------------------------------------------------------------
// small conversion / setup kernels
// ---------------------------------------------------------------------------
__global__ void cvt_flat(const float* __restrict__ s, short* __restrict__ d, int n){
  const int i = (blockIdx.x*256 + threadIdx.x)*4;
  if (i >= n) return;
  float4 v = *(const float4*)(s+i);
  union { uint2 u; short s4[4]; } o;
  o.s4[0]=f2bf_s(v.x); o.s4[1]=f2bf_s(v.y); o.s4[2]=f2bf_s(v.z); o.s4[3]=f2bf_s(v.w);
  *(uint2*)(d+i) = o.u;
}

__global__ void cvt_w1(const float* __restrict__ sw1, const float* __restrict__ dw1,
                       short* __restrict__ dst){
  const int i = (blockIdx.x*256 + threadIdx.x)*4;
  if (i >= 2359296) return;
  const int mat = i / 589824, rem = i % 589824;
  const int r = rem / 768, c = rem % 768;
  const float* src = (mat < 2 ? sw1 : dw1) + (size_t)r*1536 + (mat&1)*768 + c;
  float4 v = *(const float4*)src;
  union { uint2 u; short s4[4]; } o;
  o.s4[0]=f2bf_s(v.x); o.s4[1]=f2bf_s(v.y); o.s4[2]=f2bf_s(v.z); o.s4[3]=f2bf_s(v.w);
  *(uint2*)(dst+i) = o.u;
}

__global__ void concat_x(const float* __restrict__ sup, const float* __restrict__ qry,
                         float* __restrict__ xf, short* __restrict__ comb){
  const int i = (blockIdx.x*256 + threadIdx.x)*4;
  if (i >= 196608) return;
  const int row = i / 768, col = i % 768;
  const float* s = (row < 128 ? sup + (size_t)row*768 : qry + (size_t)(row-128)*768) + col;
  float4 v = *(const float4*)s;
  *(float4*)(xf+i) = v;
  union { uint2 u; short s4[4]; } o;
  o.s4[0]=f2bf_s(v.x); o.s4[1]=f2bf_s(v.y); o.s4[2]=f2bf_s(v.z); o.s4[3]=f2bf_s(v.w);
  *(uint2*)(comb + (size_t)row*1536 + col) = o.u;
}

__global__ void cls2_kernel(const short* __restrict__ hc, const float* __restrict__ w2,
                            const float* __restrict__ b2, float* __restrict__ preds){
  const int t = blockIdx.x*192 + threadIdx.x;
  if (t >= 384) return;
  const int m = t/3, c = t - m*3;
  float s = b2[c];
  for (int k = 0; k < 384; ++k)
    s += bf_s2f(hc[m*384+k]) * w2[c*384+k];
  preds[m*3+c] = s;
}

// ---------------------------------------------------------------------------
// workspace layout (bytes)
// ---------------------------------------------------------------------------
static const size_t OFF_P      = 8388608;    // 2359296  (256x2304 f32)
static const size_t OFF_XF     = 10747904;   // 786432
static const size_t OFF_Y      = 11534336;   // 786432
static const size_t OFF_COMB   = 12320768;   // 786432   (256x1536 bf16)
static const size_t OFF_CB     = 13107200;   // 2097152  (256x4096 bf16)
static const size_t OFF_W1X4   = 15204352;   // 4718592  (4x 768x768 bf16)
static const size_t OFF_W2S    = 19922944;   // 24576
static const size_t OFF_W2D    = 19947520;   // 24576
static const size_t OFF_AW1    = 19972096;   // 7077888
static const size_t OFF_AW2    = 27049984;   // 3538944
static const size_t OFF_CW1    = 30588928;   // 589824
static const size_t OFF_TBUF   = 50053120;   // 6291456  (256x12288 bf16)
static const size_t OFF_HID1   = 56344576;   // 393216
static const size_t OFF_HIDC   = 56737792;   // 98304

extern "C" void kernel_launch(void* const* d_in, const int* in_sizes, int n_in,
                              void* d_out, int out_size, void* d_ws, size_t ws_size,
                              hipStream_t stream)
{
  (void)in_sizes; (void)n_in; (void)out_size; (void)ws_size;
  const float* sup    = (const float*)d_in[0];
  const float* qry    = (const float*)d_in[2];
  const float* sim_w1 = (const float*)d_in[3];
  const float* sim_b1 = (const float*)d_in[4];
  const float* sim_w2 = (const float*)d_in[5];
  const float* sim_b2 = (const float*)d_in[6];
  const float* div_w1 = (const float*)d_in[7];
  const float* div_b1 = (const float*)d_in[8];
  const float* div_w2 = (const float*)d_in[9];
  const float* div_b2 = (const float*)d_in[10];
  const float* rel_w  = (const float*)d_in[11];
  const float* rel_b  = (const float*)d_in[12];
  const float* agg_w1 = (const float*)d_in[13];
  const float* agg_b1 = (const float*)d_in[14];
  const float* agg_w2 = (const float*)d_in[15];
  const float* agg_b2 = (const float*)d_in[16];
  const float* ln_g   = (const float*)d_in[17];
  const float* ln_b   = (const float*)d_in[18];
  const float* cls_w1 = (const float*)d_in[19];
  const float* cls_b1 = (const float*)d_in[20];
  const float* cls_w2 = (const float*)d_in[21];
  const float* cls_b2 = (const float*)d_in[22];

  char* w = (char*)d_ws;
  float* P    = (float*)(w + OFF_P);
  float* XF   = (float*)(w + OFF_XF);
  float* Y    = (float*)(w + OFF_Y);
  short* COMB = (short*)(w + OFF_COMB);
  short* CB   = (short*)(w + OFF_CB);
  short* W1X4 = (short*)(w + OFF_W1X4);
  short* W2S  = (short*)(w + OFF_W2S);
  short* W2D  = (short*)(w + OFF_W2D);
  short* AW1  = (short*)(w + OFF_AW1);
  short* AW2  = (short*)(w + OFF_AW2);
  short* CW1  = (short*)(w + OFF_CW1);
  short* TBUF = (short*)(w + OFF_TBUF);
  short* HID1 = (short*)(w + OFF_HID1);
  short* HIDC = (short*)(w + OFF_HIDC);

  float* preds = (float*)d_out;
  float* simo  = preds + 384;
  float* divo  = simo + 1048576;
  float* xout  = divo + 1048576;

  // weight conversions (f32 -> bf16)
  cvt_flat<<<12,   256, 0, stream>>>(sim_w2, W2S, 12288);
  cvt_flat<<<12,   256, 0, stream>>>(div_w2, W2D, 12288);
  cvt_flat<<<3456, 256, 0, stream>>>(agg_w1, AW1, 3538944);
  cvt_flat<<<1728, 256, 0, stream>>>(agg_w2, AW2, 1769472);
  cvt_flat<<<288,  256, 0, stream>>>(cls_w1, CW1, 294912);
  cvt_w1<<<2304,   256, 0, stream>>>(sim_w1, div_w1, W1X4);
  concat_x<<<192,  256, 0, stream>>>(sup, qry, XF, COMB);

  // P = x @ [wa_sim | wb_sim | wa_div]^T   (M=256, N=2304, K=768)
  gemm_bt<64,64,0><<<144, 256, 0, stream>>>(COMB, 1536, W1X4, 768, P, nullptr, 2304,
                                            nullptr, 768, 36);

  // fused relations: div GEMM + sim + softmax + symmetrize + C
  relfused<<<dim3(4,256), 512, 0, stream>>>(COMB, W1X4 + (size_t)3*589824, P,
                                            div_b1, sim_b1, W2D, W2S,
                                            div_b2, sim_b2, simo, divo, CB);

  for (int l = 0; l < 3; ++l){
    // T = x @ rel_w^T + rb  (fused f32->bf16 on rel_w)
    gemm_relT<<<192, 512, 0, stream>>>(COMB, rel_w + (size_t)l*9437184, TBUF,
                                       rel_b + l*12288);
    // msg = C(256x4096) @ T(4096x768) / 255 -> comb[:, 768:]
    gemm_bn_msg<<<48, 256, 0, stream>>>(CB, 4096, TBUF, 768, COMB, 1536, 768,
                                        4096, 12, 1.f/255.f);
    // hid1 = relu(comb @ aw1^T + ab1)
    gemm_bt<64,64,2><<<48, 256, 0, stream>>>(COMB, 1536, AW1 + (size_t)l*1179648, 1536,
                                             nullptr, HID1, 768, agg_b1 + l*768, 1536, 12);
    // y = hid1 @ aw2^T + ab2
    gemm_bt<64,64,3><<<48, 256, 0, stream>>>(HID1, 768, AW2 + (size_t)l*589824, 768,
                                             Y, nullptr, 768, agg_b2 + l*768, 768, 12);
    ln_kernel<<<256, 256, 0, stream>>>(Y, XF, COMB, ln_g + l*768, ln_b + l*768,
                                       (l == 2) ? xout : nullptr);
  }

  // classifier
  gemm_bt<64,64,2><<<12, 256, 0, stream>>>(COMB + (size_t)128*1536, 1536, CW1, 768,
                                           nullptr, HIDC, 384, cls_b1, 768, 6);
  cls2_kernel<<<2, 192, 0, stream>>>(HIDC, cls_w2, cls_b2, preds);
}

// Round 3
// 543.861 us; speedup vs baseline: 1.1106x; 1.1106x over previous
//
#include <hip/hip_runtime.h>
#include <hip/hip_bf16.h>

// ---------------------------------------------------------------------------
// DualRelationsPropagation on MI355X (gfx950) — round 3
// Relations stage rewritten: exact upper-triangle tiling (4i x 16j = 64 pair
// rows per block, 544 blocks), A=|x_j-x_i| built IN REGISTERS (v_perm pack),
// counted-vmcnt double-buffered B staging with raw s_barrier (no full drain),
// fused sim + both 2nd GEMMs + softmax + symmetrize + C write. No atomics.
// Layer loop: 32x64 tiles for CU fill.
// ---------------------------------------------------------------------------

typedef __attribute__((ext_vector_type(8))) short s16x8;
typedef __attribute__((ext_vector_type(4))) float f32x4;

__device__ __forceinline__ short f2bf_s(float f){
  union { __hip_bfloat16 h; short s; } u; u.h = __float2bfloat16(f); return u.s;
}
__device__ __forceinline__ float bf_s2f(short s){
  union { __hip_bfloat16 h; short s; } u; u.s = s; return __bfloat162float(u.h);
}
__device__ __forceinline__ f32x4 mfma16(s16x8 a, s16x8 b, f32x4 c){
  return __builtin_amdgcn_mfma_f32_16x16x32_bf16(a, b, c, 0, 0, 0);
}
__device__ __forceinline__ void gload16(void* lds, const void* g){
  __builtin_amdgcn_global_load_lds((const __attribute__((address_space(1))) void*)g,
                                   (__attribute__((address_space(3))) void*)lds,
                                   16, 0, 0);
}
// pack two non-negative f32 to bf16 pair (truncating) in one v_perm
__device__ __forceinline__ unsigned pack2bf(float lo, float hi){
  return __builtin_amdgcn_perm(__float_as_uint(hi), __float_as_uint(lo), 0x07060302u);
}
// |a-b| elementwise on 8 bf16, truncating pack, sign cleared via mask
__device__ __forceinline__ s16x8 absdiff_bf(uint4 a, uint4 b){
  union { s16x8 v; unsigned u[4]; } o;
  const unsigned au[4] = {a.x,a.y,a.z,a.w}, bu[4] = {b.x,b.y,b.z,b.w};
  #pragma unroll
  for (int w = 0; w < 4; ++w){
    float lo = __uint_as_float(au[w] << 16)        - __uint_as_float(bu[w] << 16);
    float hi = __uint_as_float(au[w] & 0xffff0000u) - __uint_as_float(bu[w] & 0xffff0000u);
    o.u[w] = __builtin_amdgcn_perm(__float_as_uint(hi), __float_as_uint(lo), 0x07060302u)
             & 0x7fff7fffu;
  }
  return o.v;
}

__device__ __forceinline__ char* swz64(short* base, int row, int col){
  return (char*)base + row*128 + ((col*2) ^ ((row&7)<<4));
}

// ---------------------------------------------------------------------------
// Generic bf16 GEMM: C(MxN) = A(MxK) * B^T  (B stored N x K row-major).
// EPI: 0 = f32 out, 2 = relu(+bias) -> bf16, 3 = +bias -> f32
// ---------------------------------------------------------------------------
template<int BM, int BN, int EPI>
__global__ __launch_bounds__(256) void gemm_bt(
    const short* __restrict__ A, int lda,
    const short* __restrict__ B, int ldb,
    float* __restrict__ Cf, short* __restrict__ Cb, int ldc,
    const float* __restrict__ bias, int K, int NT)
{
  __shared__ short As[BM*64];
  __shared__ short Bs[BN*64];
  const int tid = threadIdx.x, lane = tid & 63, wid = tid >> 6;
  const int nt = blockIdx.x % NT, mt = blockIdx.x / NT;
  const int m0 = mt*BM, n0 = nt*BN;
  const int wm0 = (wid>>1)*(BM/2), wn0 = (wid&1)*(BN/2);
  f32x4 acc[BM/32][BN/32] = {};
  for (int k0 = 0; k0 < K; k0 += 64){
    #pragma unroll
    for (int rd = 0; rd < (BM*64)/2048; ++rd){
      int ei = rd*2048 + tid*8, row = ei>>6, col = ei&63;
      *(uint4*)swz64(As,row,col) = *(const uint4*)(A + (size_t)(m0+row)*lda + k0 + col);
    }
    #pragma unroll
    for (int rd = 0; rd < (BN*64)/2048; ++rd){
      int ei = rd*2048 + tid*8, row = ei>>6, col = ei&63;
      *(uint4*)swz64(Bs,row,col) = *(const uint4*)(B + (size_t)(n0+row)*ldb + k0 + col);
    }
    __syncthreads();
    #pragma unroll
    for (int kk = 0; kk < 2; ++kk){
      const int kc = kk*32 + (lane>>4)*8;
      s16x8 af[BM/32], bfv[BN/32];
      #pragma unroll
      for (int mi = 0; mi < BM/32; ++mi)
        af[mi] = *(const s16x8*)swz64(As, wm0 + mi*16 + (lane&15), kc);
      #pragma unroll
      for (int ni = 0; ni < BN/32; ++ni)
        bfv[ni] = *(const s16x8*)swz64(Bs, wn0 + ni*16 + (lane&15), kc);
      #pragma unroll
      for (int mi = 0; mi < BM/32; ++mi)
        #pragma unroll
        for (int ni = 0; ni < BN/32; ++ni)
          acc[mi][ni] = mfma16(af[mi], bfv[ni], acc[mi][ni]);
    }
    __syncthreads();
  }
  #pragma unroll
  for (int mi = 0; mi < BM/32; ++mi){
    #pragma unroll
    for (int ni = 0; ni < BN/32; ++ni){
      const int gcol = n0 + wn0 + ni*16 + (lane&15);
      float bv = (EPI != 0) ? bias[gcol] : 0.f;
      #pragma unroll
      for (int r = 0; r < 4; ++r){
        const int grow = m0 + wm0 + mi*16 + (lane>>4)*4 + r;
        float v = acc[mi][ni][r] + bv;
        if (EPI == 2) v = fmaxf(v, 0.f);
        if (EPI == 0 || EPI == 3) Cf[(size_t)grow*ldc + gcol] = v;
        else                      Cb[(size_t)grow*ldc + gcol] = f2bf_s(v);
      }
    }
  }
}

// ---------------------------------------------------------------------------
// msg GEMM: C(MxN) = A(MxK) * B(KxN), B natural K-major (T as 4096x768).
// ---------------------------------------------------------------------------
template<int BM>
__global__ __launch_bounds__(256) void gemm_bn_msg(
    const short* __restrict__ A, int lda,
    const short* __restrict__ B, int ldb,
    short* __restrict__ Co, int ldc, int ccol0,
    int K, int NT, float scale)
{
  __shared__ short As[BM*64];
  __shared__ short Bs[64*64];
  const int tid = threadIdx.x, lane = tid & 63, wid = tid >> 6;
  const int nt = blockIdx.x % NT, mt = blockIdx.x / NT;
  const int m0 = mt*BM, n0 = nt*64;
  const int wm0 = (wid>>1)*(BM/2), wn0 = (wid&1)*32;
  f32x4 acc[BM/32][2] = {};
  for (int k0 = 0; k0 < K; k0 += 64){
    #pragma unroll
    for (int rd = 0; rd < (BM*64)/2048; ++rd){
      int ei = rd*2048 + tid*8, row = ei>>6, col = ei&63;
      *(uint4*)swz64(As,row,col) = *(const uint4*)(A + (size_t)(m0+row)*lda + k0 + col);
    }
    #pragma unroll
    for (int rd = 0; rd < 2; ++rd){
      int ei = rd*2048 + tid*8, kr = ei>>6, nc = ei&63;
      union { uint4 v; short s[8]; } u;
      u.v = *(const uint4*)(B + (size_t)(k0+kr)*ldb + n0 + nc);
      #pragma unroll
      for (int e = 0; e < 8; ++e)
        *(short*)((char*)Bs + (nc+e)*128 + ((kr*2) ^ (((nc+e)&7)<<4))) = u.s[e];
    }
    __syncthreads();
    #pragma unroll
    for (int kk = 0; kk < 2; ++kk){
      const int kc = kk*32 + (lane>>4)*8;
      s16x8 af[BM/32], bfv[2];
      #pragma unroll
      for (int mi = 0; mi < BM/32; ++mi)
        af[mi] = *(const s16x8*)swz64(As, wm0 + mi*16 + (lane&15), kc);
      #pragma unroll
      for (int ni = 0; ni < 2; ++ni)
        bfv[ni] = *(const s16x8*)swz64(Bs, wn0 + ni*16 + (lane&15), kc);
      #pragma unroll
      for (int mi = 0; mi < BM/32; ++mi)
        #pragma unroll
        for (int ni = 0; ni < 2; ++ni)
          acc[mi][ni] = mfma16(af[mi], bfv[ni], acc[mi][ni]);
    }
    __syncthreads();
  }
  #pragma unroll
  for (int mi = 0; mi < BM/32; ++mi)
    #pragma unroll
    for (int ni = 0; ni < 2; ++ni){
      const int gcol = n0 + wn0 + ni*16 + (lane&15);
      #pragma unroll
      for (int r = 0; r < 4; ++r){
        const int grow = m0 + wm0 + mi*16 + (lane>>4)*4 + r;
        Co[(size_t)grow*ldc + ccol0 + gcol] = f2bf_s(acc[mi][ni][r] * scale);
      }
    }
}

// ---------------------------------------------------------------------------
// Pair-relations kernel. Block = 4 i's x 16 j's = 64 pair rows; 544 blocks
// cover {i<=j} exactly (crossing tiles masked on write). 256 thr = 4 waves.
// Per nt (3 x 256 n-cols): pipelined div GEMM (A in regs, Bs dbuf'd via
// counted vmcnt + raw s_barrier) -> hid_div -> 16-wide logits MFMA; then
// hid_sim from P (precomputed, b1 folded) -> sim logits MFMA. Epilogue:
// bias + softmax (shfl over 16 lanes) + symmetrize + sim/div/C writes.
// ---------------------------------------------------------------------------
__device__ __forceinline__ void stageB(short* dstbase, const short* Bsrc,
                                       int n0, int k0, int wv, int lane){
  #pragma unroll
  for (int q = 0; q < 8; ++q){
    const int d = (wv*8+q)*1024 + lane*16;
    const int row = d>>7, c = d&127;
    gload16((char*)dstbase + (wv*8+q)*1024,
            (const char*)Bsrc + (size_t)(n0+row)*1536 + (size_t)k0*2 + (c ^ ((row&7)<<4)));
  }
}

__global__ __launch_bounds__(256, 2) void pairrel(
    const short* __restrict__ xb,      // COMB, x in cols [0,768), stride 1536
    const short* __restrict__ wbdiv,   // 768x768 bf16 (B^T layout)
    const float* __restrict__ P2,      // 256x2304: [pa_sim+b1s | pb_sim | pa_div+b1d]
    const short* __restrict__ w2d_g, const short* __restrict__ w2s_g, // 16x768 bf16
    const float* __restrict__ b2d, const float* __restrict__ b2s,
    float* __restrict__ simo, float* __restrict__ divo, short* __restrict__ CBo)
{
  __shared__ short R0[32768];    // 64KB: Bs dbuf (2 x 256rows x 64cols) / hid (64x256)
  __shared__ short w2l[4096];    // 8KB: w2 chunk (16 x 256)
  const int tid = threadIdx.x, lane = tid & 63, wv = tid >> 6;
  const int wm = wv >> 1, wc = wv & 1;

  int b = blockIdx.x;
  int jb = (int)((sqrtf(2.f*(float)b + 1.f) - 1.f)*0.5f);
  while (2*(jb+1)*(jb+2) <= b) ++jb;
  while (2*jb*(jb+1) > b) --jb;
  const int i0 = (b - 2*jb*(jb+1))*4;
  const int j0 = jb*16;

  const short* xj  = xb + (size_t)(j0 + (lane&15))*1536 + (lane>>4)*8;
  const short* xi0 = xb + (size_t)(i0 + wm*2    )*1536 + (lane>>4)*8;
  const short* xi1 = xb + (size_t)(i0 + wm*2 + 1)*1536 + (lane>>4)*8;

  f32x4 acc2d = {0.f,0.f,0.f,0.f}, acc2s = {0.f,0.f,0.f,0.f};

  for (int nt = 0; nt < 3; ++nt){
    const int n0 = nt*256;
    // prologue: stage w2_div (2 gloads) + Bs buf0 (8 gloads)
    #pragma unroll
    for (int q = 0; q < 2; ++q){
      const int d = (wv*2+q)*1024 + lane*16;
      const int rr = d>>9, c = d&511;
      gload16((char*)w2l + (wv*2+q)*1024,
              (const char*)w2d_g + (size_t)rr*1536 + (size_t)n0*2 + (c ^ ((rr&7)<<4)));
    }
    stageB(R0, wbdiv, n0, 0, wv, lane);

    f32x4 acc[2][8] = {};
    for (int t = 0; t < 12; ++t){
      // x loads for this step (older than next stage -> compiler wait leaves stage in flight)
      uint4 uj0  = *(const uint4*)(xj  + t*64);
      uint4 uj1  = *(const uint4*)(xj  + t*64 + 32);
      uint4 ui00 = *(const uint4*)(xi0 + t*64);
      uint4 ui01 = *(const uint4*)(xi0 + t*64 + 32);
      uint4 ui10 = *(const uint4*)(xi1 + t*64);
      uint4 ui11 = *(const uint4*)(xi1 + t*64 + 32);
      // drain OWN current-buffer stage (8 oldest), leave x loads (6) in flight
      asm volatile("s_waitcnt vmcnt(6)" ::: "memory");
      __builtin_amdgcn_s_barrier();            // all waves' cur stages now visible
      if (t < 11)
        stageB(R0 + ((t+1)&1)*16384, wbdiv, n0, (t+1)*64, wv, lane);
      __builtin_amdgcn_sched_barrier(0);       // pin stage issue before compute/next-x
      const char* bufc = (const char*)(R0 + (t&1)*16384);
      #pragma unroll
      for (int kk = 0; kk < 2; ++kk){
        s16x8 af0 = absdiff_bf(kk ? uj1 : uj0, kk ? ui01 : ui00);
        s16x8 af1 = absdiff_bf(kk ? uj1 : uj0, kk ? ui11 : ui10);
        const int colb = (kk*32 + (lane>>4)*8)*2;
        s16x8 bfv[8];
        #pragma unroll
        for (int ni = 0; ni < 8; ++ni){
          const int row = wc*128 + ni*16 + (lane&15);
          bfv[ni] = *(const s16x8*)(bufc + row*128 + (colb ^ ((row&7)<<4)));
        }
        #pragma unroll
        for (int ni = 0; ni < 8; ++ni){
          acc[0][ni] = mfma16(af0, bfv[ni], acc[0][ni]);
          acc[1][ni] = mfma16(af1, bfv[ni], acc[1][ni]);
        }
      }
    }
    __syncthreads();
    // hid_div = relu(G + pa_div + b1d) -> R0 as [64][256] bf16 (512B rows, swizzled)
    #pragma unroll
    for (int mi = 0; mi < 2; ++mi){
      #pragma unroll
      for (int ni = 0; ni < 8; ++ni){
        const int col = wc*128 + ni*16 + (lane&15);
        const float pav = P2[(size_t)(i0 + wm*2 + mi)*2304 + 1536 + n0 + col];
        #pragma unroll
        for (int r = 0; r < 4; ++r){
          const int row = wm*32 + mi*16 + (lane>>4)*4 + r;
          const float v = fmaxf(acc[mi][ni][r] + pav, 0.f);
          *(short*)((char*)R0 + row*512 + ((col*2) ^ ((row&7)<<4))) =
              (short)(__float_as_uint(v) >> 16);
        }
      }
    }
    __syncthreads();
    // div 2nd GEMM: logits(64 x 16) over K=256, accumulated across nt
    {
      const int arow = wv*16 + (lane&15);
      const int wrow = lane & 15;
      #pragma unroll
      for (int kk = 0; kk < 8; ++kk){
        const int colb = (kk*32 + (lane>>4)*8)*2;
        s16x8 a = *(const s16x8*)((const char*)R0  + arow*512 + (colb ^ ((arow&7)<<4)));
        s16x8 w = *(const s16x8*)((const char*)w2l + wrow*512 + (colb ^ ((wrow&7)<<4)));
        acc2d = mfma16(a, w, acc2d);
      }
    }
    __syncthreads();
    // stage w2_sim; build hid_sim = relu(pa_sim+b1s + pb_sim)
    #pragma unroll
    for (int q = 0; q < 2; ++q){
      const int d = (wv*2+q)*1024 + lane*16;
      const int rr = d>>9, c = d&511;
      gload16((char*)w2l + (wv*2+q)*1024,
              (const char*)w2s_g + (size_t)rr*1536 + (size_t)n0*2 + (c ^ ((rr&7)<<4)));
    }
    {
      const int row = tid>>2, c0 = (tid&3)*64;
      const int isim = i0 + (row>>4), jsim = j0 + (row&15);
      const float* pap = P2 + (size_t)isim*2304 + n0 + c0;
      const float* pbp = P2 + (size_t)jsim*2304 + 768 + n0 + c0;
      #pragma unroll
      for (int cc = 0; cc < 64; cc += 8){
        float4 a0 = *(const float4*)(pap+cc), a1 = *(const float4*)(pap+cc+4);
        float4 q0 = *(const float4*)(pbp+cc), q1 = *(const float4*)(pbp+cc+4);
        uint4 o;
        o.x = pack2bf(fmaxf(a0.x+q0.x,0.f), fmaxf(a0.y+q0.y,0.f));
        o.y = pack2bf(fmaxf(a0.z+q0.z,0.f), fmaxf(a0.w+q0.w,0.f));
        o.z = pack2bf(fmaxf(a1.x+q1.x,0.f), fmaxf(a1.y+q1.y,0.f));
        o.w = pack2bf(fmaxf(a1.z+q1.z,0.f), fmaxf(a1.w+q1.w,0.f));
        *(uint4*)((char*)R0 + row*512 + (((c0+cc)*2) ^ ((row&7)<<4))) = o;
      }
    }
    asm volatile("s_waitcnt vmcnt(0)" ::: "memory");
    __syncthreads();
    // sim 2nd GEMM
    {
      const int arow = wv*16 + (lane&15);
      const int wrow = lane & 15;
      #pragma unroll
      for (int kk = 0; kk < 8; ++kk){
        const int colb = (kk*32 + (lane>>4)*8)*2;
        s16x8 a = *(const s16x8*)((const char*)R0  + arow*512 + (colb ^ ((arow&7)<<4)));
        s16x8 w = *(const s16x8*)((const char*)w2l + wrow*512 + (colb ^ ((wrow&7)<<4)));
        acc2s = mfma16(a, w, acc2s);
      }
    }
    __syncthreads();  // before next-nt prologue overwrites R0/w2l
  }

  // epilogue: +b2, softmax over r (16 lanes), symmetrize, write
  const int r_ = lane & 15;
  float vd[4], vs[4], outd[4], outs[4];
  {
    const float bd = b2d[r_], bs = b2s[r_];
    #pragma unroll
    for (int r = 0; r < 4; ++r){ vd[r] = acc2d[r] + bd; vs[r] = acc2s[r] + bs; }
  }
  #pragma unroll
  for (int r = 0; r < 4; ++r){
    float m = vd[r];
    m = fmaxf(m, __shfl_xor(m,1)); m = fmaxf(m, __shfl_xor(m,2));
    m = fmaxf(m, __shfl_xor(m,4)); m = fmaxf(m, __shfl_xor(m,8));
    float e = expf(vd[r]-m), s = e;
    s += __shfl_xor(s,1); s += __shfl_xor(s,2); s += __shfl_xor(s,4); s += __shfl_xor(s,8);
    outd[r] = e/s;
    m = vs[r];
    m = fmaxf(m, __shfl_xor(m,1)); m = fmaxf(m, __shfl_xor(m,2));
    m = fmaxf(m, __shfl_xor(m,4)); m = fmaxf(m, __shfl_xor(m,8));
    e = expf(vs[r]-m); s = e;
    s += __shfl_xor(s,1); s += __shfl_xor(s,2); s += __shfl_xor(s,4); s += __shfl_xor(s,8);
    outs[r] = e/s;
  }
  const int iw = i0 + wv;
  #pragma unroll
  for (int r = 0; r < 4; ++r){
    const int j = j0 + (lane>>4)*4 + r;
    if (j > iw){
      const size_t pij = (((size_t)iw<<8) + j)*16 + r_;
      const size_t pji = (((size_t)j<<8) + iw)*16 + r_;
      divo[pij] = outd[r]; divo[pji] = outd[r];
      simo[pij] = outs[r]; simo[pji] = outs[r];
      const short cb = f2bf_s(0.5f*(outd[r]+outs[r]));
      CBo[pij] = cb; CBo[pji] = cb;
    } else if (j == iw){
      const size_t pii = (((size_t)iw<<8) + iw)*16 + r_;
      divo[pii] = 0.f; simo[pii] = 0.f; CBo[pii] = 0;
    }
  }
}

// ---------------------------------------------------------------------------
// T GEMM with fused rel_w f32->bf16 (from r2, unchanged)
// ---------------------------------------------------------------------------
__global__ __launch_bounds__(512) void gemm_relT(
    const short* __restrict__ A,     // COMB, lda=1536
    const float* __restrict__ Bf,    // 12288 x 768 f32
    short* __restrict__ T,           // 256 x 12288 bf16
    const float* __restrict__ bias)  // 12288
{
  __shared__ short As[256*64];
  __shared__ short Bs[64*64];
  const int tid = threadIdx.x, lane = tid & 63, wv = tid >> 6;
  const int n0 = blockIdx.x*64;
  const int wm = wv >> 1, wn = wv & 1;
  const int lswz = (lane & 7) << 4;
  const int kfrag = (lane>>4)*16;
  const int brow = tid >> 3, bc0 = (tid & 7)*8;
  int abase[4], bbase[2];
  #pragma unroll
  for (int mi = 0; mi < 4; ++mi) abase[mi] = (wm*64 + mi*16 + (lane&15))*128;
  #pragma unroll
  for (int ni = 0; ni < 2; ++ni) bbase[ni] = (wn*32 + ni*16 + (lane&15))*128;
  f32x4 acc[4][2] = {};
  for (int k0 = 0; k0 < 768; k0 += 64){
    #pragma unroll
    for (int q = 0; q < 4; ++q){
      const int d = wv*4096 + q*1024 + lane*16;
      const int row = d>>7, c = d&127;
      gload16((char*)As + wv*4096 + q*1024,
              (const char*)A + (size_t)row*3072 + (size_t)k0*2 + (c ^ ((row&7)<<4)));
    }
    {
      const float* bp = Bf + (size_t)(n0+brow)*768 + k0 + bc0;
      float4 v0 = *(const float4*)bp, v1 = *(const float4*)(bp+4);
      union { uint4 v; unsigned u[4]; } uo;
      uo.u[0] = pack2bf(fabsf(v0.x)*0.f + v0.x, v0.y); // plain pack (values signed)
      // NOTE: pack2bf truncates; for signed weights keep sign bits via perm (no mask)
      uo.u[0] = __builtin_amdgcn_perm(__float_as_uint(v0.y), __float_as_uint(v0.x), 0x07060302u);
      uo.u[1] = __builtin_amdgcn_perm(__float_as_uint(v0.w), __float_as_uint(v0.z), 0x07060302u);
      uo.u[2] = __builtin_amdgcn_perm(__float_as_uint(v1.y), __float_as_uint(v1.x), 0x07060302u);
      uo.u[3] = __builtin_amdgcn_perm(__float_as_uint(v1.w), __float_as_uint(v1.z), 0x07060302u);
      *(uint4*)((char*)Bs + brow*128 + ((bc0*2) ^ ((brow&7)<<4))) = uo.v;
    }
    __syncthreads();
    #pragma unroll
    for (int kk = 0; kk < 2; ++kk){
      const int kb = (kk*64 + kfrag) ^ lswz;
      s16x8 af[4], bfv[2];
      #pragma unroll
      for (int mi = 0; mi < 4; ++mi) af[mi] = *(const s16x8*)((char*)As + abase[mi] + kb);
      #pragma unroll
      for (int ni = 0; ni < 2; ++ni) bfv[ni] = *(const s16x8*)((char*)Bs + bbase[ni] + kb);
      #pragma unroll
      for (int mi = 0; mi < 4; ++mi)
        #pragma unroll
        for (int ni = 0; ni < 2; ++ni)
          acc[mi][ni] = mfma16(af[mi], bfv[ni], acc[mi][ni]);
    }
    __syncthreads();
  }
  #pragma unroll
  for (int mi = 0; mi < 4; ++mi)
    #pragma unroll
    for (int ni = 0; ni < 2; ++ni){
      const int nn = n0 + wn*32 + ni*16 + (lane&15);
      const float bv = bias[nn];
      #pragma unroll
      for (int r = 0; r < 4; ++r){
        const int row = wm*64 + mi*16 + (lane>>4)*4 + r;
        T[(size_t)row*12288 + nn] = f2bf_s(acc[mi][ni][r] + bv);
      }
    }
}

// ---------------------------------------------------------------------------
// LayerNorm(y + x) -> x (f32), comb[:, :768] (bf16), optional d_out x
// ---------------------------------------------------------------------------
__global__ __launch_bounds__(256) void ln_kernel(
    const float* __restrict__ y, float* __restrict__ x, short* __restrict__ combx,
    const float* __restrict__ g, const float* __restrict__ b, float* __restrict__ xfinal)
{
  const int row = blockIdx.x, tid = threadIdx.x;
  float tv[3]; float s = 0.f, s2 = 0.f;
  #pragma unroll
  for (int c = 0; c < 3; ++c){
    const int idx = tid + c*256;
    const float v = y[row*768+idx] + x[row*768+idx];
    tv[c] = v; s += v; s2 += v*v;
  }
  #pragma unroll
  for (int off = 32; off > 0; off >>= 1){ s += __shfl_down(s, off); s2 += __shfl_down(s2, off); }
  __shared__ float red[8];
  const int wid = tid >> 6, lane = tid & 63;
  if (lane == 0){ red[wid] = s; red[wid+4] = s2; }
  __syncthreads();
  if (tid == 0){
    red[0] = red[0]+red[1]+red[2]+red[3];
    red[4] = red[4]+red[5]+red[6]+red[7];
  }
  __syncthreads();
  const float mu = red[0]*(1.f/768.f);
  const float var = red[4]*(1.f/768.f) - mu*mu;
  const float inv = rsqrtf(var + 1e-5f);
  #pragma unroll
  for (int c = 0; c < 3; ++c){
    const int idx = tid + c*256;
    const float v = (tv[c]-mu)*inv*g[idx] + b[idx];
    x[row*768+idx] = v;
    combx[(size_t)row*1536 + idx] = f2bf_s(v);
    if (xfinal) xfinal[row*768+idx] = v;
  }
}

// ---------------------------------------------------------------------------
// small conversion / setup kernels
// ---------------------------------------------------------------------------
__global__ void cvt_flat(const float* __restrict__ s, short* __restrict__ d, int n){
  const int i = (blockIdx.x*256 + threadIdx.x)*4;
  if (i >= n) return;
  float4 v = *(const float4*)(s+i);
  union { uint2 u; short s4[4]; } o;
  o.s4[0]=f2bf_s(v.x); o.s4[1]=f2bf_s(v.y); o.s4[2]=f2bf_s(v.z); o.s4[3]=f2bf_s(v.w);
  *(uint2*)(d+i) = o.u;
}

__global__ void cvt_w1(const float* __restrict__ sw1, const float* __restrict__ dw1,
                       short* __restrict__ dst){
  const int i = (blockIdx.x*256 + threadIdx.x)*4;
  if (i >= 2359296) return;
  const int mat = i / 589824, rem = i % 589824;
  const int r = rem / 768, c = rem % 768;
  const float* src = (mat < 2 ? sw1 : dw1) + (size_t)r*1536 + (mat&1)*768 + c;
  float4 v = *(const float4*)src;
  union { uint2 u; short s4[4]; } o;
  o.s4[0]=f2bf_s(v.x); o.s4[1]=f2bf_s(v.y); o.s4[2]=f2bf_s(v.z); o.s4[3]=f2bf_s(v.w);
  *(uint2*)(dst+i) = o.u;
}

__global__ void concat_x(const float* __restrict__ sup, const float* __restrict__ qry,
                         float* __restrict__ xf, short* __restrict__ comb){
  const int i = (blockIdx.x*256 + threadIdx.x)*4;
  if (i >= 196608) return;
  const int row = i / 768, col = i % 768;
  const float* s = (row < 128 ? sup + (size_t)row*768 : qry + (size_t)(row-128)*768) + col;
  float4 v = *(const float4*)s;
  *(float4*)(xf+i) = v;
  union { uint2 u; short s4[4]; } o;
  o.s4[0]=f2bf_s(v.x); o.s4[1]=f2bf_s(v.y); o.s4[2]=f2bf_s(v.z); o.s4[3]=f2bf_s(v.w);
  *(uint2*)(comb + (size_t)row*1536 + col) = o.u;
}

__global__ void build_bias(const float* __restrict__ b1s, const float* __restrict__ b1d,
                           float* __restrict__ out){
  const int t = blockIdx.x*256 + threadIdx.x;
  if (t >= 2304) return;
  out[t] = (t < 768) ? b1s[t] : ((t < 1536) ? 0.f : b1d[t-1536]);
}

__global__ void cls2_kernel(const short* __restrict__ hc, const float* __restrict__ w2,
                            const float* __restrict__ b2, float* __restrict__ preds){
  const int t = blockIdx.x*192 + threadIdx.x;
  if (t >= 384) return;
  const int m = t/3, c = t - m*3;
  float s = b2[c];
  for (int k = 0; k < 384; ++k)
    s += bf_s2f(hc[m*384+k]) * w2[c*384+k];
  preds[m*3+c] = s;
}

// ---------------------------------------------------------------------------
// workspace layout (bytes)
// ---------------------------------------------------------------------------
static const size_t OFF_B1CAT = 0;           // 9216
static const size_t OFF_P     = 8388608;     // 2359296  (256x2304 f32)
static const size_t OFF_XF    = 10747904;    // 786432
static const size_t OFF_Y     = 11534336;    // 786432
static const size_t OFF_COMB  = 12320768;    // 786432   (256x1536 bf16)
static const size_t OFF_CB    = 13107200;    // 2097152  (256x4096 bf16)
static const size_t OFF_W1X4  = 15204352;    // 4718592  (4x 768x768 bf16)
static const size_t OFF_W2S   = 19922944;    // 24576
static const size_t OFF_W2D   = 19947520;    // 24576
static const size_t OFF_AW1   = 19972096;    // 7077888
static const size_t OFF_AW2   = 27049984;    // 3538944
static const size_t OFF_CW1   = 30588928;    // 589824
static const size_t OFF_TBUF  = 50053120;    // 6291456  (256x12288 bf16)
static const size_t OFF_HID1  = 56344576;    // 393216
static const size_t OFF_HIDC  = 56737792;    // 98304

extern "C" void kernel_launch(void* const* d_in, const int* in_sizes, int n_in,
                              void* d_out, int out_size, void* d_ws, size_t ws_size,
                              hipStream_t stream)
{
  (void)in_sizes; (void)n_in; (void)out_size; (void)ws_size;
  const float* sup    = (const float*)d_in[0];
  const float* qry    = (const float*)d_in[2];
  const float* sim_w1 = (const float*)d_in[3];
  const float* sim_b1 = (const float*)d_in[4];
  const float* sim_w2 = (const float*)d_in[5];
  const float* sim_b2 = (const float*)d_in[6];
  const float* div_w1 = (const float*)d_in[7];
  const float* div_b1 = (const float*)d_in[8];
  const float* div_w2 = (const float*)d_in[9];
  const float* div_b2 = (const float*)d_in[10];
  const float* rel_w  = (const float*)d_in[11];
  const float* rel_b  = (const float*)d_in[12];
  const float* agg_w1 = (const float*)d_in[13];
  const float* agg_b1 = (const float*)d_in[14];
  const float* agg_w2 = (const float*)d_in[15];
  const float* agg_b2 = (const float*)d_in[16];
  const float* ln_g   = (const float*)d_in[17];
  const float* ln_b   = (const float*)d_in[18];
  const float* cls_w1 = (const float*)d_in[19];
  const float* cls_b1 = (const float*)d_in[20];
  const float* cls_w2 = (const float*)d_in[21];
  const float* cls_b2 = (const float*)d_in[22];

  char* w = (char*)d_ws;
  float* B1C  = (float*)(w + OFF_B1CAT);
  float* P2   = (float*)(w + OFF_P);
  float* XF   = (float*)(w + OFF_XF);
  float* Y    = (float*)(w + OFF_Y);
  short* COMB = (short*)(w + OFF_COMB);
  short* CB   = (short*)(w + OFF_CB);
  short* W1X4 = (short*)(w + OFF_W1X4);
  short* W2S  = (short*)(w + OFF_W2S);
  short* W2D  = (short*)(w + OFF_W2D);
  short* AW1  = (short*)(w + OFF_AW1);
  short* AW2  = (short*)(w + OFF_AW2);
  short* CW1  = (short*)(w + OFF_CW1);
  short* TBUF = (short*)(w + OFF_TBUF);
  short* HID1 = (short*)(w + OFF_HID1);
  short* HIDC = (short*)(w + OFF_HIDC);

  float* preds = (float*)d_out;
  float* simo  = preds + 384;
  float* divo  = simo + 1048576;
  float* xout  = divo + 1048576;

  // setup / weight conversions
  cvt_flat<<<12,   256, 0, stream>>>(sim_w2, W2S, 12288);
  cvt_flat<<<12,   256, 0, stream>>>(div_w2, W2D, 12288);
  cvt_flat<<<3456, 256, 0, stream>>>(agg_w1, AW1, 3538944);
  cvt_flat<<<1728, 256, 0, stream>>>(agg_w2, AW2, 1769472);
  cvt_flat<<<288,  256, 0, stream>>>(cls_w1, CW1, 294912);
  cvt_w1<<<2304,   256, 0, stream>>>(sim_w1, div_w1, W1X4);
  concat_x<<<192,  256, 0, stream>>>(sup, qry, XF, COMB);
  build_bias<<<9,  256, 0, stream>>>(sim_b1, div_b1, B1C);

  // P2 = x @ [wa_sim | wb_sim | wa_div]^T + [b1s|0|b1d]  (M=256,N=2304,K=768)
  gemm_bt<64,64,3><<<144, 256, 0, stream>>>(COMB, 1536, W1X4, 768, P2, nullptr, 2304,
                                            B1C, 768, 36);

  // fused relations (544 triangle blocks)
  pairrel<<<544, 256, 0, stream>>>(COMB, W1X4 + (size_t)3*589824, P2,
                                   W2D, W2S, div_b2, sim_b2, simo, divo, CB);

  for (int l = 0; l < 3; ++l){
    gemm_relT<<<192, 512, 0, stream>>>(COMB, rel_w + (size_t)l*9437184, TBUF,
                                       rel_b + l*12288);
    gemm_bn_msg<32><<<96, 256, 0, stream>>>(CB, 4096, TBUF, 768, COMB, 1536, 768,
                                            4096, 12, 1.f/255.f);
    gemm_bt<32,64,2><<<96, 256, 0, stream>>>(COMB, 1536, AW1 + (size_t)l*1179648, 1536,
                                             nullptr, HID1, 768, agg_b1 + l*768, 1536, 12);
    gemm_bt<32,64,3><<<96, 256, 0, stream>>>(HID1, 768, AW2 + (size_t)l*589824, 768,
                                             Y, nullptr, 768, agg_b2 + l*768, 768, 12);
    ln_kernel<<<256, 256, 0, stream>>>(Y, XF, COMB, ln_g + l*768, ln_b + l*768,
                                       (l == 2) ? xout : nullptr);
  }

  gemm_bt<32,64,2><<<24, 256, 0, stream>>>(COMB + (size_t)128*1536, 1536, CW1, 768,
                                           nullptr, HIDC, 384, cls_b1, 768, 6);
  cls2_kernel<<<2, 192, 0, stream>>>(HIDC, cls_w2, cls_b2, preds);
}

// Round 4
// 349.159 us; speedup vs baseline: 1.7299x; 1.5576x over previous
//
#include <hip/hip_runtime.h>
#include <hip/hip_bf16.h>

// ---------------------------------------------------------------------------
// DualRelationsPropagation on MI355X (gfx950) — round 4
// Theme: OCCUPANCY. pairrel2: 1632 blocks x 256thr x 32KB LDS (4 blocks/CU),
// plain 2-phase staging, partial-logit slabs (no atomics). Layer loop: split-K
// msg (8x512), BK=128 small GEMMs (half the barrier chain). No hand pipelining
// anywhere — wave-level overlap (m114) does the latency hiding.
// ---------------------------------------------------------------------------

typedef __attribute__((ext_vector_type(8))) short s16x8;
typedef __attribute__((ext_vector_type(4))) float f32x4;

__device__ __forceinline__ short f2bf_s(float f){
  union { __hip_bfloat16 h; short s; } u; u.h = __float2bfloat16(f); return u.s;
}
__device__ __forceinline__ float bf_s2f(short s){
  union { __hip_bfloat16 h; short s; } u; u.s = s; return __bfloat162float(u.h);
}
__device__ __forceinline__ f32x4 mfma16(s16x8 a, s16x8 b, f32x4 c){
  return __builtin_amdgcn_mfma_f32_16x16x32_bf16(a, b, c, 0, 0, 0);
}
__device__ __forceinline__ void gload16(void* lds, const void* g){
  __builtin_amdgcn_global_load_lds((const __attribute__((address_space(1))) void*)g,
                                   (__attribute__((address_space(3))) void*)lds,
                                   16, 0, 0);
}
__device__ __forceinline__ unsigned pack2bf(float lo, float hi){
  return __builtin_amdgcn_perm(__float_as_uint(hi), __float_as_uint(lo), 0x07060302u);
}
// |a-b| on 8 packed bf16 (truncating pack, sign cleared)
__device__ __forceinline__ s16x8 absdiff_bf(uint4 a, uint4 b){
  union { s16x8 v; unsigned u[4]; } o;
  const unsigned au[4] = {a.x,a.y,a.z,a.w}, bu[4] = {b.x,b.y,b.z,b.w};
  #pragma unroll
  for (int w = 0; w < 4; ++w){
    float lo = __uint_as_float(au[w] << 16)         - __uint_as_float(bu[w] << 16);
    float hi = __uint_as_float(au[w] & 0xffff0000u) - __uint_as_float(bu[w] & 0xffff0000u);
    o.u[w] = __builtin_amdgcn_perm(__float_as_uint(hi), __float_as_uint(lo), 0x07060302u)
             & 0x7fff7fffu;
  }
  return o.v;
}

// decode triangle block index -> (i0 quad, j0 16-row tile)
__device__ __forceinline__ void tri_decode(int b, int& i0, int& j0){
  int jb = (int)((sqrtf(2.f*(float)b + 1.f) - 1.f)*0.5f);
  while (2*(jb+1)*(jb+2) <= b) ++jb;
  while (2*jb*(jb+1) > b) --jb;
  i0 = (b - 2*jb*(jb+1))*4;
  j0 = jb*16;
}

// ---------------------------------------------------------------------------
// Generic bf16 GEMM, BK=128: C(MxN) = A(MxK) * B^T (B stored N x K row-major).
// BN=64. 256 thr = 4 waves 2x2. A,B staged via global_load_lds (swizzled src).
// EPI: 2 = relu(+bias) -> bf16, 3 = +bias -> f32
// ---------------------------------------------------------------------------
template<int BM, int EPI>
__global__ __launch_bounds__(256) void gemm_bt2(
    const short* __restrict__ A, int lda,
    const short* __restrict__ B, int ldb,
    float* __restrict__ Cf, short* __restrict__ Cb, int ldc,
    const float* __restrict__ bias, int K, int NT)
{
  __shared__ short As[BM*128];   // 256B rows
  __shared__ short Bs[64*128];
  const int tid = threadIdx.x, lane = tid & 63, wid = tid >> 6;
  const int nt = blockIdx.x % NT, mt = blockIdx.x / NT;
  const int m0 = mt*BM, n0 = nt*64;
  const int wm0 = (wid>>1)*(BM/2), wn0 = (wid&1)*32;
  f32x4 acc[BM/32][2] = {};
  for (int k0 = 0; k0 < K; k0 += 128){
    if (k0) __syncthreads();
    #pragma unroll
    for (int q = 0; q < BM/16; ++q){
      const int d = (wid*(BM/16)+q)*1024 + lane*16;
      const int row = d>>8, c = d&255;
      gload16((char*)As + (wid*(BM/16)+q)*1024,
              (const char*)A + (size_t)(m0+row)*lda*2 + (size_t)k0*2 + (c ^ ((row&7)<<4)));
    }
    #pragma unroll
    for (int q = 0; q < 4; ++q){
      const int d = (wid*4+q)*1024 + lane*16;
      const int row = d>>8, c = d&255;
      gload16((char*)Bs + (wid*4+q)*1024,
              (const char*)B + (size_t)(n0+row)*ldb*2 + (size_t)k0*2 + (c ^ ((row&7)<<4)));
    }
    __syncthreads();
    #pragma unroll
    for (int kk = 0; kk < 4; ++kk){
      const int colb = (kk*32 + (lane>>4)*8)*2;
      s16x8 af[BM/32], bfv[2];
      #pragma unroll
      for (int mi = 0; mi < BM/32; ++mi){
        const int row = wm0 + mi*16 + (lane&15);
        af[mi] = *(const s16x8*)((char*)As + row*256 + (colb ^ ((row&7)<<4)));
      }
      #pragma unroll
      for (int ni = 0; ni < 2; ++ni){
        const int row = wn0 + ni*16 + (lane&15);
        bfv[ni] = *(const s16x8*)((char*)Bs + row*256 + (colb ^ ((row&7)<<4)));
      }
      #pragma unroll
      for (int mi = 0; mi < BM/32; ++mi)
        #pragma unroll
        for (int ni = 0; ni < 2; ++ni)
          acc[mi][ni] = mfma16(af[mi], bfv[ni], acc[mi][ni]);
    }
  }
  #pragma unroll
  for (int mi = 0; mi < BM/32; ++mi){
    #pragma unroll
    for (int ni = 0; ni < 2; ++ni){
      const int gcol = n0 + wn0 + ni*16 + (lane&15);
      const float bv = bias[gcol];
      #pragma unroll
      for (int r = 0; r < 4; ++r){
        const int grow = m0 + wm0 + mi*16 + (lane>>4)*4 + r;
        float v = acc[mi][ni][r] + bv;
        if (EPI == 2) v = fmaxf(v, 0.f);
        if (EPI == 3) Cf[(size_t)grow*ldc + gcol] = v;
        else          Cb[(size_t)grow*ldc + gcol] = f2bf_s(v);
      }
    }
  }
}

// ---------------------------------------------------------------------------
// msg GEMM, split-K: MSGF += CB(256x4096-chunk) * TBUF(chunk x 768) * scale.
// grid (48, 8): 64x64 tile, K-chunk 512 (8 steps of BK64). atomicAdd f32 out.
// ---------------------------------------------------------------------------
__global__ __launch_bounds__(256) void gemm_msg(
    const short* __restrict__ A,    // CB, lda 4096
    const short* __restrict__ B,    // TBUF as (4096 x 768) K-major
    float* __restrict__ Cf, float scale)
{
  __shared__ short As[64*64];      // 128B rows
  __shared__ short Bs[64*64];      // transposed: [n][k]
  const int tid = threadIdx.x, lane = tid & 63, wid = tid >> 6;
  const int mt = blockIdx.x / 12, nt = blockIdx.x % 12;
  const int m0 = mt*64, n0 = nt*64, kc0 = blockIdx.y*512;
  const int wm0 = (wid>>1)*32, wn0 = (wid&1)*32;
  f32x4 acc[2][2] = {};
  for (int s = 0; s < 8; ++s){
    const int k0 = kc0 + s*64;
    if (s) __syncthreads();
    #pragma unroll
    for (int q = 0; q < 2; ++q){
      const int d = (wid*2+q)*1024 + lane*16;
      const int row = d>>7, c = d&127;
      gload16((char*)As + (wid*2+q)*1024,
              (const char*)A + (size_t)(m0+row)*8192 + (size_t)k0*2 + (c ^ ((row&7)<<4)));
    }
    #pragma unroll
    for (int rd = 0; rd < 2; ++rd){
      int ei = rd*2048 + tid*8, kr = ei>>6, nc = ei&63;
      union { uint4 v; short s4[8]; } u;
      u.v = *(const uint4*)(B + (size_t)(k0+kr)*768 + n0 + nc);
      #pragma unroll
      for (int e = 0; e < 8; ++e)
        *(short*)((char*)Bs + (nc+e)*128 + ((kr*2) ^ (((nc+e)&7)<<4))) = u.s4[e];
    }
    __syncthreads();
    #pragma unroll
    for (int kk = 0; kk < 2; ++kk){
      const int colb = (kk*32 + (lane>>4)*8)*2;
      s16x8 af[2], bfv[2];
      #pragma unroll
      for (int mi = 0; mi < 2; ++mi){
        const int row = wm0 + mi*16 + (lane&15);
        af[mi] = *(const s16x8*)((char*)As + row*128 + (colb ^ ((row&7)<<4)));
      }
      #pragma unroll
      for (int ni = 0; ni < 2; ++ni){
        const int row = wn0 + ni*16 + (lane&15);
        bfv[ni] = *(const s16x8*)((char*)Bs + row*128 + (colb ^ ((row&7)<<4)));
      }
      #pragma unroll
      for (int mi = 0; mi < 2; ++mi)
        #pragma unroll
        for (int ni = 0; ni < 2; ++ni)
          acc[mi][ni] = mfma16(af[mi], bfv[ni], acc[mi][ni]);
    }
  }
  #pragma unroll
  for (int mi = 0; mi < 2; ++mi)
    #pragma unroll
    for (int ni = 0; ni < 2; ++ni){
      const int gcol = n0 + wn0 + ni*16 + (lane&15);
      #pragma unroll
      for (int r = 0; r < 4; ++r){
        const int grow = m0 + wm0 + mi*16 + (lane>>4)*4 + r;
        atomicAdd(&Cf[(size_t)grow*768 + gcol], acc[mi][ni][r]*scale);
      }
    }
}

// ---------------------------------------------------------------------------
// pairrel2: div-relation partial logits. Grid dim3(544,3): triangle block
// (4 i x 16 j), nt = 256-col chunk. 256 thr, 32KB LDS, 4 blocks/CU target.
// A = |x_j - x_i| in registers; Bs (wbdiv chunk) via gload_lds, 2-phase.
// hid -> Bs reuse -> 16-wide logits MFMA (w2 frags from global) -> slab.
// ---------------------------------------------------------------------------
__global__ __launch_bounds__(256, 4) void pairrel2(
    const short* __restrict__ xb,      // COMB, x cols [0,768), stride 1536
    const short* __restrict__ wbdiv,   // 768x768 bf16 (B^T layout)
    const float* __restrict__ P2,      // 256x2304: [pa_s+b1s | pb_s | pa_d+b1d]
    const short* __restrict__ w2d_g,   // 16x768 bf16
    float* __restrict__ Ldp)           // [3][256][256][16] f32 partials
{
  __shared__ short Bs[256*64];         // 32KB; later hid [64][256]
  const int tid = threadIdx.x, lane = tid & 63, wv = tid >> 6;
  const int wm = wv >> 1, wc = wv & 1;
  int i0, j0; tri_decode(blockIdx.x, i0, j0);
  const int nt = blockIdx.y, n0 = nt*256;

  const short* xjp = xb + (size_t)(j0 + (lane&15))*1536 + (lane>>4)*8;
  const short* xi0p = xb + (size_t)(i0 + wm*2    )*1536 + (lane>>4)*8;
  const short* xi1p = xb + (size_t)(i0 + wm*2 + 1)*1536 + (lane>>4)*8;

  f32x4 acc[2][8] = {};
  for (int t = 0; t < 12; ++t){
    if (t) __syncthreads();            // WAR on Bs
    #pragma unroll
    for (int q = 0; q < 8; ++q){       // stage wbdiv rows n0..n0+255, k-cols t*64..
      const int d = (wv*8+q)*1024 + lane*16;
      const int row = d>>7, c = d&127;
      gload16((char*)Bs + (wv*8+q)*1024,
              (const char*)wbdiv + (size_t)(n0+row)*1536 + (size_t)t*128 + (c ^ ((row&7)<<4)));
    }
    // x loads issued before barrier (barrier's vmcnt drain covers them)
    uint4 uja  = *(const uint4*)(xjp  + t*64);
    uint4 ujb  = *(const uint4*)(xjp  + t*64 + 32);
    uint4 ui0a = *(const uint4*)(xi0p + t*64);
    uint4 ui0b = *(const uint4*)(xi0p + t*64 + 32);
    uint4 ui1a = *(const uint4*)(xi1p + t*64);
    uint4 ui1b = *(const uint4*)(xi1p + t*64 + 32);
    __syncthreads();
    #pragma unroll
    for (int kk = 0; kk < 2; ++kk){
      s16x8 af0 = absdiff_bf(kk ? ujb : uja, kk ? ui0b : ui0a);
      s16x8 af1 = absdiff_bf(kk ? ujb : uja, kk ? ui1b : ui1a);
      const int colb = (kk*32 + (lane>>4)*8)*2;
      s16x8 bfv[8];
      #pragma unroll
      for (int ni = 0; ni < 8; ++ni){
        const int row = wc*128 + ni*16 + (lane&15);
        bfv[ni] = *(const s16x8*)((char*)Bs + row*128 + (colb ^ ((row&7)<<4)));
      }
      #pragma unroll
      for (int ni = 0; ni < 8; ++ni){
        acc[0][ni] = mfma16(af0, bfv[ni], acc[0][ni]);
        acc[1][ni] = mfma16(af1, bfv[ni], acc[1][ni]);
      }
    }
  }
  __syncthreads();
  // hid = relu(G + pa_div + b1d) -> Bs as [64 pair-rows][256 cols], 512B rows
  #pragma unroll
  for (int mi = 0; mi < 2; ++mi){
    #pragma unroll
    for (int ni = 0; ni < 8; ++ni){
      const int col = wc*128 + ni*16 + (lane&15);
      const float pav = P2[(size_t)(i0 + wm*2 + mi)*2304 + 1536 + n0 + col];
      #pragma unroll
      for (int r = 0; r < 4; ++r){
        const int row = wm*32 + mi*16 + (lane>>4)*4 + r;
        const float v = fmaxf(acc[mi][ni][r] + pav, 0.f);
        *(short*)((char*)Bs + row*512 + ((col*2) ^ ((row&7)<<4))) =
            (short)(__float_as_uint(v) >> 16);
      }
    }
  }
  __syncthreads();
  // logits partial (64 pair-rows x 16), K=256; w2 frags straight from global
  f32x4 acc2 = {0.f,0.f,0.f,0.f};
  const int arow = wv*16 + (lane&15);
  #pragma unroll
  for (int q = 0; q < 8; ++q){
    const int colb = (q*32 + (lane>>4)*8)*2;
    s16x8 a = *(const s16x8*)((const char*)Bs + arow*512 + (colb ^ ((arow&7)<<4)));
    s16x8 w = *(const s16x8*)(w2d_g + (size_t)(lane&15)*768 + n0 + q*32 + (lane>>4)*8);
    acc2 = mfma16(a, w, acc2);
  }
  const int r_ = lane & 15;
  #pragma unroll
  for (int r = 0; r < 4; ++r){
    const int p = wv*16 + (lane>>4)*4 + r;
    const int i = i0 + (p>>4), j = j0 + (p&15);
    Ldp[(size_t)nt*1048576 + (((size_t)i<<8) + j)*16 + r_] = acc2[r];
  }
}

// ---------------------------------------------------------------------------
// simpart: sim logits (final). Grid 544 triangle blocks, nt-loop inside.
// hid_sim = relu(pa_i + pb_j (+b1 folded)) -> LDS -> 16-wide MFMA.
// ---------------------------------------------------------------------------
__global__ __launch_bounds__(256) void simpart(
    const float* __restrict__ P2,
    const short* __restrict__ w2s_g,
    float* __restrict__ Ls)            // [256][256][16] f32
{
  __shared__ short Hs[64*256];         // 32KB
  const int tid = threadIdx.x, lane = tid & 63, wv = tid >> 6;
  int i0, j0; tri_decode(blockIdx.x, i0, j0);
  const int arow = wv*16 + (lane&15);
  f32x4 acc2 = {0.f,0.f,0.f,0.f};
  for (int nt = 0; nt < 3; ++nt){
    const int n0 = nt*256;
    if (nt) __syncthreads();
    {
      const int row = tid>>2, c0 = (tid&3)*64;
      const float* pap = P2 + (size_t)(i0 + (row>>4))*2304 + n0 + c0;
      const float* pbp = P2 + (size_t)(j0 + (row&15))*2304 + 768 + n0 + c0;
      #pragma unroll
      for (int cc = 0; cc < 64; cc += 8){
        float4 a0 = *(const float4*)(pap+cc), a1 = *(const float4*)(pap+cc+4);
        float4 q0 = *(const float4*)(pbp+cc), q1 = *(const float4*)(pbp+cc+4);
        uint4 o;
        o.x = pack2bf(fmaxf(a0.x+q0.x,0.f), fmaxf(a0.y+q0.y,0.f));
        o.y = pack2bf(fmaxf(a0.z+q0.z,0.f), fmaxf(a0.w+q0.w,0.f));
        o.z = pack2bf(fmaxf(a1.x+q1.x,0.f), fmaxf(a1.y+q1.y,0.f));
        o.w = pack2bf(fmaxf(a1.z+q1.z,0.f), fmaxf(a1.w+q1.w,0.f));
        *(uint4*)((char*)Hs + row*512 + (((c0+cc)*2) ^ ((row&7)<<4))) = o;
      }
    }
    __syncthreads();
    #pragma unroll
    for (int q = 0; q < 8; ++q){
      const int colb = (q*32 + (lane>>4)*8)*2;
      s16x8 a = *(const s16x8*)((const char*)Hs + arow*512 + (colb ^ ((arow&7)<<4)));
      s16x8 w = *(const s16x8*)(w2s_g + (size_t)(lane&15)*768 + n0 + q*32 + (lane>>4)*8);
      acc2 = mfma16(a, w, acc2);
    }
  }
  const int r_ = lane & 15;
  #pragma unroll
  for (int r = 0; r < 4; ++r){
    const int p = wv*16 + (lane>>4)*4 + r;
    const int i = i0 + (p>>4), j = j0 + (p&15);
    Ls[(((size_t)i<<8) + j)*16 + r_] = acc2[r];
  }
}

// ---------------------------------------------------------------------------
// finisher: sum div partials, +b2, softmax both, symmetrize, write sim/div/C
// ---------------------------------------------------------------------------
__global__ __launch_bounds__(256) void finisher2(
    const float* __restrict__ Ls, const float* __restrict__ Ldp,
    const float* __restrict__ b2s, const float* __restrict__ b2d,
    float* __restrict__ simo, float* __restrict__ divo, short* __restrict__ Cb)
{
  const int p = blockIdx.x*256 + threadIdx.x;
  const int i = p >> 8, j = p & 255;
  float so[16], dd[16];
  if (i == j){
    #pragma unroll
    for (int r = 0; r < 16; ++r){ so[r] = 0.f; dd[r] = 0.f; }
  } else {
    const int si = i < j ? i : j, sj = i < j ? j : i;
    const size_t base = (((size_t)si << 8) + sj) * 16;
    float mx = -1e30f, sum;
    #pragma unroll
    for (int r = 0; r < 16; ++r){ so[r] = Ls[base+r] + b2s[r]; mx = fmaxf(mx, so[r]); }
    sum = 0.f;
    #pragma unroll
    for (int r = 0; r < 16; ++r){ so[r] = expf(so[r]-mx); sum += so[r]; }
    sum = 1.f/sum;
    #pragma unroll
    for (int r = 0; r < 16; ++r) so[r] *= sum;
    mx = -1e30f;
    #pragma unroll
    for (int r = 0; r < 16; ++r){
      dd[r] = Ldp[base+r] + Ldp[base+r+1048576] + Ldp[base+r+2097152] + b2d[r];
      mx = fmaxf(mx, dd[r]);
    }
    sum = 0.f;
    #pragma unroll
    for (int r = 0; r < 16; ++r){ dd[r] = expf(dd[r]-mx); sum += dd[r]; }
    sum = 1.f/sum;
    #pragma unroll
    for (int r = 0; r < 16; ++r) dd[r] *= sum;
  }
  const size_t ob = (size_t)p * 16;
  #pragma unroll
  for (int r = 0; r < 16; ++r){
    simo[ob+r] = so[r];
    divo[ob+r] = dd[r];
    Cb[ob+r]   = f2bf_s(0.5f*(so[r]+dd[r]));
  }
}

// ---------------------------------------------------------------------------
// T GEMM with fused rel_w f32->bf16 (r2/r3, works)
// ---------------------------------------------------------------------------
__global__ __launch_bounds__(512) void gemm_relT(
    const short* __restrict__ A,     // COMB, lda=1536
    const float* __restrict__ Bf,    // 12288 x 768 f32
    short* __restrict__ T,           // 256 x 12288 bf16
    const float* __restrict__ bias)  // 12288
{
  __shared__ short As[256*64];
  __shared__ short Bs[64*64];
  const int tid = threadIdx.x, lane = tid & 63, wv = tid >> 6;
  const int n0 = blockIdx.x*64;
  const int wm = wv >> 1, wn = wv & 1;
  const int lswz = (lane & 7) << 4;
  const int kfrag = (lane>>4)*16;
  const int brow = tid >> 3, bc0 = (tid & 7)*8;
  int abase[4], bbase[2];
  #pragma unroll
  for (int mi = 0; mi < 4; ++mi) abase[mi] = (wm*64 + mi*16 + (lane&15))*128;
  #pragma unroll
  for (int ni = 0; ni < 2; ++ni) bbase[ni] = (wn*32 + ni*16 + (lane&15))*128;
  f32x4 acc[4][2] = {};
  for (int k0 = 0; k0 < 768; k0 += 64){
    if (k0) __syncthreads();
    #pragma unroll
    for (int q = 0; q < 4; ++q){
      const int d = wv*4096 + q*1024 + lane*16;
      const int row = d>>7, c = d&127;
      gload16((char*)As + wv*4096 + q*1024,
              (const char*)A + (size_t)row*3072 + (size_t)k0*2 + (c ^ ((row&7)<<4)));
    }
    {
      const float* bp = Bf + (size_t)(n0+brow)*768 + k0 + bc0;
      float4 v0 = *(const float4*)bp, v1 = *(const float4*)(bp+4);
      union { uint4 v; unsigned u[4]; } uo;
      uo.u[0] = pack2bf(v0.x, v0.y);  // truncating pack (signed ok: perm keeps sign byte)
      uo.u[1] = pack2bf(v0.z, v0.w);
      uo.u[2] = pack2bf(v1.x, v1.y);
      uo.u[3] = pack2bf(v1.z, v1.w);
      *(uint4*)((char*)Bs + brow*128 + ((bc0*2) ^ ((brow&7)<<4))) = uo.v;
    }
    __syncthreads();
    #pragma unroll
    for (int kk = 0; kk < 2; ++kk){
      const int kb = (kk*64 + kfrag) ^ lswz;
      s16x8 af[4], bfv[2];
      #pragma unroll
      for (int mi = 0; mi < 4; ++mi) af[mi] = *(const s16x8*)((char*)As + abase[mi] + kb);
      #pragma unroll
      for (int ni = 0; ni < 2; ++ni) bfv[ni] = *(const s16x8*)((char*)Bs + bbase[ni] + kb);
      #pragma unroll
      for (int mi = 0; mi < 4; ++mi)
        #pragma unroll
        for (int ni = 0; ni < 2; ++ni)
          acc[mi][ni] = mfma16(af[mi], bfv[ni], acc[mi][ni]);
    }
  }
  #pragma unroll
  for (int mi = 0; mi < 4; ++mi)
    #pragma unroll
    for (int ni = 0; ni < 2; ++ni){
      const int nn = n0 + wn*32 + ni*16 + (lane&15);
      const float bv = bias[nn];
      #pragma unroll
      for (int r = 0; r < 4; ++r){
        const int row = wm*64 + mi*16 + (lane>>4)*4 + r;
        T[(size_t)row*12288 + nn] = f2bf_s(acc[mi][ni][r] + bv);
      }
    }
}

// ---------------------------------------------------------------------------
// LayerNorm(y + x) -> x (f32), comb[:, :768] (bf16), optional d_out x
// ---------------------------------------------------------------------------
__global__ __launch_bounds__(256) void ln_kernel(
    const float* __restrict__ y, float* __restrict__ x, short* __restrict__ combx,
    const float* __restrict__ g, const float* __restrict__ b, float* __restrict__ xfinal)
{
  const int row = blockIdx.x, tid = threadIdx.x;
  float tv[3]; float s = 0.f, s2 = 0.f;
  #pragma unroll
  for (int c = 0; c < 3; ++c){
    const int idx = tid + c*256;
    const float v = y[row*768+idx] + x[row*768+idx];
    tv[c] = v; s += v; s2 += v*v;
  }
  #pragma unroll
  for (int off = 32; off > 0; off >>= 1){ s += __shfl_down(s, off); s2 += __shfl_down(s2, off); }
  __shared__ float red[8];
  const int wid = tid >> 6, lane = tid & 63;
  if (lane == 0){ red[wid] = s; red[wid+4] = s2; }
  __syncthreads();
  if (tid == 0){
    red[0] = red[0]+red[1]+red[2]+red[3];
    red[4] = red[4]+red[5]+red[6]+red[7];
  }
  __syncthreads();
  const float mu = red[0]*(1.f/768.f);
  const float var = red[4]*(1.f/768.f) - mu*mu;
  const float inv = rsqrtf(var + 1e-5f);
  #pragma unroll
  for (int c = 0; c < 3; ++c){
    const int idx = tid + c*256;
    const float v = (tv[c]-mu)*inv*g[idx] + b[idx];
    x[row*768+idx] = v;
    combx[(size_t)row*1536 + idx] = f2bf_s(v);
    if (xfinal) xfinal[row*768+idx] = v;
  }
}

// ---------------------------------------------------------------------------
// small conversion / setup kernels
// ---------------------------------------------------------------------------
__global__ void cvt_flat(const float* __restrict__ s, short* __restrict__ d, int n){
  const int i = (blockIdx.x*256 + threadIdx.x)*4;
  if (i >= n) return;
  float4 v = *(const float4*)(s+i);
  union { uint2 u; short s4[4]; } o;
  o.s4[0]=f2bf_s(v.x); o.s4[1]=f2bf_s(v.y); o.s4[2]=f2bf_s(v.z); o.s4[3]=f2bf_s(v.w);
  *(uint2*)(d+i) = o.u;
}

__global__ void cvt_w1(const float* __restrict__ sw1, const float* __restrict__ dw1,
                       short* __restrict__ dst){
  const int i = (blockIdx.x*256 + threadIdx.x)*4;
  if (i >= 2359296) return;
  const int mat = i / 589824, rem = i % 589824;
  const int r = rem / 768, c = rem % 768;
  const float* src = (mat < 2 ? sw1 : dw1) + (size_t)r*1536 + (mat&1)*768 + c;
  float4 v = *(const float4*)src;
  union { uint2 u; short s4[4]; } o;
  o.s4[0]=f2bf_s(v.x); o.s4[1]=f2bf_s(v.y); o.s4[2]=f2bf_s(v.z); o.s4[3]=f2bf_s(v.w);
  *(uint2*)(dst+i) = o.u;
}

__global__ void cvt_msg(const float* __restrict__ msgf, short* __restrict__ comb){
  const int i = (blockIdx.x*256 + threadIdx.x)*4;
  if (i >= 196608) return;
  const int row = i / 768, col = i % 768;
  float4 v = *(const float4*)(msgf + i);
  union { uint2 u; short s4[4]; } o;
  o.s4[0]=f2bf_s(v.x); o.s4[1]=f2bf_s(v.y); o.s4[2]=f2bf_s(v.z); o.s4[3]=f2bf_s(v.w);
  *(uint2*)(comb + (size_t)row*1536 + 768 + col) = o.u;
}

__global__ void concat_x(const float* __restrict__ sup, const float* __restrict__ qry,
                         float* __restrict__ xf, short* __restrict__ comb){
  const int i = (blockIdx.x*256 + threadIdx.x)*4;
  if (i >= 196608) return;
  const int row = i / 768, col = i % 768;
  const float* s = (row < 128 ? sup + (size_t)row*768 : qry + (size_t)(row-128)*768) + col;
  float4 v = *(const float4*)s;
  *(float4*)(xf+i) = v;
  union { uint2 u; short s4[4]; } o;
  o.s4[0]=f2bf_s(v.x); o.s4[1]=f2bf_s(v.y); o.s4[2]=f2bf_s(v.z); o.s4[3]=f2bf_s(v.w);
  *(uint2*)(comb + (size_t)row*1536 + col) = o.u;
}

__global__ void build_bias(const float* __restrict__ b1s, const float* __restrict__ b1d,
                           float* __restrict__ out){
  const int t = blockIdx.x*256 + threadIdx.x;
  if (t >= 2304) return;
  out[t] = (t < 768) ? b1s[t] : ((t < 1536) ? 0.f : b1d[t-1536]);
}

__global__ void cls2_kernel(const short* __restrict__ hc, const float* __restrict__ w2,
                            const float* __restrict__ b2, float* __restrict__ preds){
  const int t = blockIdx.x*192 + threadIdx.x;
  if (t >= 384) return;
  const int m = t/3, c = t - m*3;
  float s = b2[c];
  for (int k = 0; k < 384; ++k)
    s += bf_s2f(hc[m*384+k]) * w2[c*384+k];
  preds[m*3+c] = s;
}

// ---------------------------------------------------------------------------
// workspace layout (bytes, total ~47.4 MB)
// ---------------------------------------------------------------------------
static const size_t OFF_B1CAT = 0;          // 9216
static const size_t OFF_LS    = 16384;      // 4194304
static const size_t OFF_MSGF  = 4210688;    // 786432
static const size_t OFF_LDP   = 5242880;    // 12582912
static const size_t OFF_P     = 17825792;   // 2359296
static const size_t OFF_XF    = 20185088;   // 786432
static const size_t OFF_Y     = 20971520;   // 786432
static const size_t OFF_COMB  = 21757952;   // 786432
static const size_t OFF_CB    = 22544384;   // 2097152
static const size_t OFF_W1X4  = 24641536;   // 4718592
static const size_t OFF_W2S   = 29360128;   // 24576
static const size_t OFF_W2D   = 29384704;   // 24576
static const size_t OFF_AW1   = 29409280;   // 7077888
static const size_t OFF_AW2   = 36487168;   // 3538944
static const size_t OFF_CW1   = 40026112;   // 589824
static const size_t OFF_TBUF  = 40615936;   // 6291456
static const size_t OFF_HID1  = 46907392;   // 393216
static const size_t OFF_HIDC  = 47300608;   // 98304

extern "C" void kernel_launch(void* const* d_in, const int* in_sizes, int n_in,
                              void* d_out, int out_size, void* d_ws, size_t ws_size,
                              hipStream_t stream)
{
  (void)in_sizes; (void)n_in; (void)out_size; (void)ws_size;
  const float* sup    = (const float*)d_in[0];
  const float* qry    = (const float*)d_in[2];
  const float* sim_w1 = (const float*)d_in[3];
  const float* sim_b1 = (const float*)d_in[4];
  const float* sim_w2 = (const float*)d_in[5];
  const float* sim_b2 = (const float*)d_in[6];
  const float* div_w1 = (const float*)d_in[7];
  const float* div_b1 = (const float*)d_in[8];
  const float* div_w2 = (const float*)d_in[9];
  const float* div_b2 = (const float*)d_in[10];
  const float* rel_w  = (const float*)d_in[11];
  const float* rel_b  = (const float*)d_in[12];
  const float* agg_w1 = (const float*)d_in[13];
  const float* agg_b1 = (const float*)d_in[14];
  const float* agg_w2 = (const float*)d_in[15];
  const float* agg_b2 = (const float*)d_in[16];
  const float* ln_g   = (const float*)d_in[17];
  const float* ln_b   = (const float*)d_in[18];
  const float* cls_w1 = (const float*)d_in[19];
  const float* cls_b1 = (const float*)d_in[20];
  const float* cls_w2 = (const float*)d_in[21];
  const float* cls_b2 = (const float*)d_in[22];

  char* w = (char*)d_ws;
  float* B1C  = (float*)(w + OFF_B1CAT);
  float* LS   = (float*)(w + OFF_LS);
  float* MSGF = (float*)(w + OFF_MSGF);
  float* LDP  = (float*)(w + OFF_LDP);
  float* P2   = (float*)(w + OFF_P);
  float* XF   = (float*)(w + OFF_XF);
  float* Y    = (float*)(w + OFF_Y);
  short* COMB = (short*)(w + OFF_COMB);
  short* CB   = (short*)(w + OFF_CB);
  short* W1X4 = (short*)(w + OFF_W1X4);
  short* W2S  = (short*)(w + OFF_W2S);
  short* W2D  = (short*)(w + OFF_W2D);
  short* AW1  = (short*)(w + OFF_AW1);
  short* AW2  = (short*)(w + OFF_AW2);
  short* CW1  = (short*)(w + OFF_CW1);
  short* TBUF = (short*)(w + OFF_TBUF);
  short* HID1 = (short*)(w + OFF_HID1);
  short* HIDC = (short*)(w + OFF_HIDC);

  float* preds = (float*)d_out;
  float* simo  = preds + 384;
  float* divo  = simo + 1048576;
  float* xout  = divo + 1048576;

  // setup / weight conversions
  cvt_flat<<<12,   256, 0, stream>>>(sim_w2, W2S, 12288);
  cvt_flat<<<12,   256, 0, stream>>>(div_w2, W2D, 12288);
  cvt_flat<<<3456, 256, 0, stream>>>(agg_w1, AW1, 3538944);
  cvt_flat<<<1728, 256, 0, stream>>>(agg_w2, AW2, 1769472);
  cvt_flat<<<288,  256, 0, stream>>>(cls_w1, CW1, 294912);
  cvt_w1<<<2304,   256, 0, stream>>>(sim_w1, div_w1, W1X4);
  concat_x<<<192,  256, 0, stream>>>(sup, qry, XF, COMB);
  build_bias<<<9,  256, 0, stream>>>(sim_b1, div_b1, B1C);

  // P2 = x @ [wa_s|wb_s|wa_d]^T + [b1s|0|b1d]   (M=256,N=2304,K=768)
  gemm_bt2<64,3><<<144, 256, 0, stream>>>(COMB, 1536, W1X4, 768, P2, nullptr, 2304,
                                          B1C, 768, 36);

  // relations
  pairrel2<<<dim3(544,3), 256, 0, stream>>>(COMB, W1X4 + (size_t)3*589824, P2, W2D, LDP);
  simpart<<<544, 256, 0, stream>>>(P2, W2S, LS);
  finisher2<<<256, 256, 0, stream>>>(LS, LDP, sim_b2, div_b2, simo, divo, CB);

  for (int l = 0; l < 3; ++l){
    gemm_relT<<<192, 512, 0, stream>>>(COMB, rel_w + (size_t)l*9437184, TBUF,
                                       rel_b + l*12288);
    hipMemsetAsync(MSGF, 0, 786432, stream);
    gemm_msg<<<dim3(48,8), 256, 0, stream>>>(CB, TBUF, MSGF, 1.f/255.f);
    cvt_msg<<<192, 256, 0, stream>>>(MSGF, COMB);
    gemm_bt2<32,2><<<96, 256, 0, stream>>>(COMB, 1536, AW1 + (size_t)l*1179648, 1536,
                                           nullptr, HID1, 768, agg_b1 + l*768, 1536, 12);
    gemm_bt2<32,3><<<96, 256, 0, stream>>>(HID1, 768, AW2 + (size_t)l*589824, 768,
                                           Y, nullptr, 768, agg_b2 + l*768, 768, 12);
    ln_kernel<<<256, 256, 0, stream>>>(Y, XF, COMB, ln_g + l*768, ln_b + l*768,
                                       (l == 2) ? xout : nullptr);
  }

  gemm_bt2<32,2><<<24, 256, 0, stream>>>(COMB + (size_t)128*1536, 1536, CW1, 768,
                                         nullptr, HIDC, 384, cls_b1, 768, 6);
  cls2_kernel<<<2, 192, 0, stream>>>(HIDC, cls_w2, cls_b2, preds);
}

// Round 5
// 320.715 us; speedup vs baseline: 1.8833x; 1.0887x over previous
//
#include <hip/hip_runtime.h>
#include <hip/hip_bf16.h>

// ---------------------------------------------------------------------------
// DualRelationsPropagation on MI355X (gfx950) — round 5
// vs r4: (1) pairrel3: double-buffered B staging with counted vmcnt + raw
// s_barrier (loads in flight across compute), cvt_pk_bf16 abs-modifier absdiff;
// (2) setup consolidated to 1 kernel; (3) msg: slab writes (no memset/atomics)
// + fused sum/cvt; (4) BN=32 small GEMMs and BM=128 relT for grid fill.
// ---------------------------------------------------------------------------

typedef __attribute__((ext_vector_type(8))) short s16x8;
typedef __attribute__((ext_vector_type(4))) float f32x4;

__device__ __forceinline__ short f2bf_s(float f){
  union { __hip_bfloat16 h; short s; } u; u.h = __float2bfloat16(f); return u.s;
}
__device__ __forceinline__ float bf_s2f(short s){
  union { __hip_bfloat16 h; short s; } u; u.s = s; return __bfloat162float(u.h);
}
__device__ __forceinline__ f32x4 mfma16(s16x8 a, s16x8 b, f32x4 c){
  return __builtin_amdgcn_mfma_f32_16x16x32_bf16(a, b, c, 0, 0, 0);
}
__device__ __forceinline__ void gload16(void* lds, const void* g){
  __builtin_amdgcn_global_load_lds((const __attribute__((address_space(1))) void*)g,
                                   (__attribute__((address_space(3))) void*)lds,
                                   16, 0, 0);
}
__device__ __forceinline__ unsigned pack2bf(float lo, float hi){
  return __builtin_amdgcn_perm(__float_as_uint(hi), __float_as_uint(lo), 0x07060302u);
}
// |a-b| on 8 packed bf16: unpack, sub, cvt_pk with abs input modifiers (RNE)
__device__ __forceinline__ s16x8 absdiff_bf(uint4 a, uint4 b){
  union { s16x8 v; unsigned u[4]; } o;
  const unsigned au[4] = {a.x,a.y,a.z,a.w}, bu[4] = {b.x,b.y,b.z,b.w};
  #pragma unroll
  for (int w = 0; w < 4; ++w){
    float dlo = __uint_as_float(au[w] << 16)         - __uint_as_float(bu[w] << 16);
    float dhi = __uint_as_float(au[w] & 0xffff0000u) - __uint_as_float(bu[w] & 0xffff0000u);
    unsigned r;
    asm("v_cvt_pk_bf16_f32 %0, abs(%1), abs(%2)" : "=v"(r) : "v"(dlo), "v"(dhi));
    o.u[w] = r;
  }
  return o.v;
}

// decode triangle block index -> (i0 quad, j0 16-row tile)
__device__ __forceinline__ void tri_decode(int b, int& i0, int& j0){
  int jb = (int)((sqrtf(2.f*(float)b + 1.f) - 1.f)*0.5f);
  while (2*(jb+1)*(jb+2) <= b) ++jb;
  while (2*jb*(jb+1) > b) --jb;
  i0 = (b - 2*jb*(jb+1))*4;
  j0 = jb*16;
}

// ---------------------------------------------------------------------------
// Generic bf16 GEMM, BK=128: C(MxN) = A(MxK) * B^T (B stored N x K row-major).
// 256 thr = 4 waves 2x2. A,B staged via global_load_lds (swizzled source).
// EPI: 2 = relu(+bias) -> bf16, 3 = +bias -> f32
// ---------------------------------------------------------------------------
template<int BM, int BN, int EPI>
__global__ __launch_bounds__(256) void gemm_bt2(
    const short* __restrict__ A, int lda,
    const short* __restrict__ B, int ldb,
    float* __restrict__ Cf, short* __restrict__ Cb, int ldc,
    const float* __restrict__ bias, int K, int NT)
{
  __shared__ short As[BM*128];   // 256B rows
  __shared__ short Bs[BN*128];
  const int tid = threadIdx.x, lane = tid & 63, wid = tid >> 6;
  const int nt = blockIdx.x % NT, mt = blockIdx.x / NT;
  const int m0 = mt*BM, n0 = nt*BN;
  const int wm0 = (wid>>1)*(BM/2), wn0 = (wid&1)*(BN/2);
  f32x4 acc[BM/32][BN/32] = {};
  for (int k0 = 0; k0 < K; k0 += 128){
    if (k0) __syncthreads();
    #pragma unroll
    for (int q = 0; q < BM/16; ++q){
      const int d = (wid*(BM/16)+q)*1024 + lane*16;
      const int row = d>>8, c = d&255;
      gload16((char*)As + (wid*(BM/16)+q)*1024,
              (const char*)A + (size_t)(m0+row)*lda*2 + (size_t)k0*2 + (c ^ ((row&7)<<4)));
    }
    #pragma unroll
    for (int q = 0; q < BN/16; ++q){
      const int d = (wid*(BN/16)+q)*1024 + lane*16;
      const int row = d>>8, c = d&255;
      gload16((char*)Bs + (wid*(BN/16)+q)*1024,
              (const char*)B + (size_t)(n0+row)*ldb*2 + (size_t)k0*2 + (c ^ ((row&7)<<4)));
    }
    __syncthreads();
    #pragma unroll
    for (int kk = 0; kk < 4; ++kk){
      const int colb = (kk*32 + (lane>>4)*8)*2;
      s16x8 af[BM/32], bfv[BN/32];
      #pragma unroll
      for (int mi = 0; mi < BM/32; ++mi){
        const int row = wm0 + mi*16 + (lane&15);
        af[mi] = *(const s16x8*)((char*)As + row*256 + (colb ^ ((row&7)<<4)));
      }
      #pragma unroll
      for (int ni = 0; ni < BN/32; ++ni){
        const int row = wn0 + ni*16 + (lane&15);
        bfv[ni] = *(const s16x8*)((char*)Bs + row*256 + (colb ^ ((row&7)<<4)));
      }
      #pragma unroll
      for (int mi = 0; mi < BM/32; ++mi)
        #pragma unroll
        for (int ni = 0; ni < BN/32; ++ni)
          acc[mi][ni] = mfma16(af[mi], bfv[ni], acc[mi][ni]);
    }
  }
  #pragma unroll
  for (int mi = 0; mi < BM/32; ++mi){
    #pragma unroll
    for (int ni = 0; ni < BN/32; ++ni){
      const int gcol = n0 + wn0 + ni*16 + (lane&15);
      const float bv = bias[gcol];
      #pragma unroll
      for (int r = 0; r < 4; ++r){
        const int grow = m0 + wm0 + mi*16 + (lane>>4)*4 + r;
        float v = acc[mi][ni][r] + bv;
        if (EPI == 2) v = fmaxf(v, 0.f);
        if (EPI == 3) Cf[(size_t)grow*ldc + gcol] = v;
        else          Cb[(size_t)grow*ldc + gcol] = f2bf_s(v);
      }
    }
  }
}

// ---------------------------------------------------------------------------
// msg GEMM, split-K slabs: slab[kc] = CB(256 x 512-chunk) * TBUF(chunk x 768).
// grid (48, 8): 64x64 tile. Plain stores (no atomics, no memset).
// ---------------------------------------------------------------------------
__global__ __launch_bounds__(256) void gemm_msg(
    const short* __restrict__ A,    // CB, lda 4096
    const short* __restrict__ B,    // TBUF as (4096 x 768) K-major
    float* __restrict__ slabs)
{
  __shared__ short As[64*64];      // 128B rows
  __shared__ short Bs[64*64];      // transposed: [n][k]
  const int tid = threadIdx.x, lane = tid & 63, wid = tid >> 6;
  const int mt = blockIdx.x / 12, nt = blockIdx.x % 12;
  const int m0 = mt*64, n0 = nt*64, kc0 = blockIdx.y*512;
  const int wm0 = (wid>>1)*32, wn0 = (wid&1)*32;
  f32x4 acc[2][2] = {};
  for (int s = 0; s < 8; ++s){
    const int k0 = kc0 + s*64;
    if (s) __syncthreads();
    #pragma unroll
    for (int q = 0; q < 2; ++q){
      const int d = (wid*2+q)*1024 + lane*16;
      const int row = d>>7, c = d&127;
      gload16((char*)As + (wid*2+q)*1024,
              (const char*)A + (size_t)(m0+row)*8192 + (size_t)k0*2 + (c ^ ((row&7)<<4)));
    }
    #pragma unroll
    for (int rd = 0; rd < 2; ++rd){
      int ei = rd*2048 + tid*8, kr = ei>>6, nc = ei&63;
      union { uint4 v; short s4[8]; } u;
      u.v = *(const uint4*)(B + (size_t)(k0+kr)*768 + n0 + nc);
      #pragma unroll
      for (int e = 0; e < 8; ++e)
        *(short*)((char*)Bs + (nc+e)*128 + ((kr*2) ^ (((nc+e)&7)<<4))) = u.s4[e];
    }
    __syncthreads();
    #pragma unroll
    for (int kk = 0; kk < 2; ++kk){
      const int colb = (kk*32 + (lane>>4)*8)*2;
      s16x8 af[2], bfv[2];
      #pragma unroll
      for (int mi = 0; mi < 2; ++mi){
        const int row = wm0 + mi*16 + (lane&15);
        af[mi] = *(const s16x8*)((char*)As + row*128 + (colb ^ ((row&7)<<4)));
      }
      #pragma unroll
      for (int ni = 0; ni < 2; ++ni){
        const int row = wn0 + ni*16 + (lane&15);
        bfv[ni] = *(const s16x8*)((char*)Bs + row*128 + (colb ^ ((row&7)<<4)));
      }
      #pragma unroll
      for (int mi = 0; mi < 2; ++mi)
        #pragma unroll
        for (int ni = 0; ni < 2; ++ni)
          acc[mi][ni] = mfma16(af[mi], bfv[ni], acc[mi][ni]);
    }
  }
  float* out = slabs + (size_t)blockIdx.y*196608;
  #pragma unroll
  for (int mi = 0; mi < 2; ++mi)
    #pragma unroll
    for (int ni = 0; ni < 2; ++ni){
      const int gcol = n0 + wn0 + ni*16 + (lane&15);
      #pragma unroll
      for (int r = 0; r < 4; ++r){
        const int grow = m0 + wm0 + mi*16 + (lane>>4)*4 + r;
        out[(size_t)grow*768 + gcol] = acc[mi][ni][r];
      }
    }
}

// sum 8 slabs, *1/255, cvt bf16 -> comb[:, 768:1536]
__global__ void msgsum(const float* __restrict__ slabs, short* __restrict__ comb){
  const int i = (blockIdx.x*256 + threadIdx.x)*4;
  if (i >= 196608) return;
  float4 s = {0.f,0.f,0.f,0.f};
  #pragma unroll
  for (int c = 0; c < 8; ++c){
    float4 v = *(const float4*)(slabs + (size_t)c*196608 + i);
    s.x += v.x; s.y += v.y; s.z += v.z; s.w += v.w;
  }
  const float sc = 1.f/255.f;
  const int row = i/768, col = i%768;
  union { uint2 u; short s4[4]; } o;
  o.s4[0]=f2bf_s(s.x*sc); o.s4[1]=f2bf_s(s.y*sc);
  o.s4[2]=f2bf_s(s.z*sc); o.s4[3]=f2bf_s(s.w*sc);
  *(uint2*)(comb + (size_t)row*1536 + 768 + col) = o.u;
}

// ---------------------------------------------------------------------------
// pairrel3: div-relation partial logits. Grid dim3(544,3). 256 thr, 64KB LDS
// (double-buffered B), 2 blocks/CU. Counted-vmcnt pipeline: stage(t+1) stays
// in flight across compute(t); raw s_barriers (no vmcnt(0) drain in loop).
// ---------------------------------------------------------------------------
__device__ __forceinline__ void stageB(short* dstbase, const short* Bsrc,
                                       int n0, int k0, int wv, int lane){
  #pragma unroll
  for (int q = 0; q < 8; ++q){
    const int d = (wv*8+q)*1024 + lane*16;
    const int row = d>>7, c = d&127;
    gload16((char*)dstbase + (wv*8+q)*1024,
            (const char*)Bsrc + (size_t)(n0+row)*1536 + (size_t)k0*2 + (c ^ ((row&7)<<4)));
  }
}

__global__ __launch_bounds__(256, 2) void pairrel3(
    const short* __restrict__ xb,      // COMB, x cols [0,768), stride 1536
    const short* __restrict__ wbdiv,   // 768x768 bf16 (B^T layout)
    const float* __restrict__ P2,      // 256x2304: [pa_s+b1s | pb_s | pa_d+b1d]
    const short* __restrict__ w2d_g,   // 16x768 bf16
    float* __restrict__ Ldp)           // [3][256][256][16] f32 partials
{
  __shared__ short Bs[2*256*64];       // 64KB dbuf; buf0 reused as hid [64][256]
  const int tid = threadIdx.x, lane = tid & 63, wv = tid >> 6;
  const int wm = wv >> 1, wc = wv & 1;
  int i0, j0; tri_decode(blockIdx.x, i0, j0);
  const int nt = blockIdx.y, n0 = nt*256;

  const short* xjp  = xb + (size_t)(j0 + (lane&15))*1536 + (lane>>4)*8;
  const short* xi0p = xb + (size_t)(i0 + wm*2    )*1536 + (lane>>4)*8;
  const short* xi1p = xb + (size_t)(i0 + wm*2 + 1)*1536 + (lane>>4)*8;

  // prologue: stage buffer 0
  stageB(Bs, wbdiv, n0, 0, wv, lane);

  f32x4 acc[2][8] = {};
  for (int t = 0; t < 12; ++t){
    if (t < 11) stageB(Bs + ((t+1)&1)*16384, wbdiv, n0, (t+1)*64, wv, lane);
    uint4 uja  = *(const uint4*)(xjp  + t*64);
    uint4 ujb  = *(const uint4*)(xjp  + t*64 + 32);
    uint4 ui0a = *(const uint4*)(xi0p + t*64);
    uint4 ui0b = *(const uint4*)(xi0p + t*64 + 32);
    uint4 ui1a = *(const uint4*)(xi1p + t*64);
    uint4 ui1b = *(const uint4*)(xi1p + t*64 + 32);
    __builtin_amdgcn_sched_barrier(0);   // all loads issued before the wait
    if (t < 11) asm volatile("s_waitcnt vmcnt(8)" ::: "memory");  // drain stage(t)+x(t)
    else        asm volatile("s_waitcnt vmcnt(0)" ::: "memory");
    __builtin_amdgcn_s_barrier();        // all waves' stage(t) visible
    __builtin_amdgcn_sched_barrier(0);
    const char* bufc = (const char*)Bs + (t&1)*32768;
    #pragma unroll
    for (int kk = 0; kk < 2; ++kk){
      s16x8 af0 = absdiff_bf(kk ? ujb : uja, kk ? ui0b : ui0a);
      s16x8 af1 = absdiff_bf(kk ? ujb : uja, kk ? ui1b : ui1a);
      const int colb = (kk*32 + (lane>>4)*8)*2;
      s16x8 bfv[8];
      #pragma unroll
      for (int ni = 0; ni < 8; ++ni){
        const int row = wc*128 + ni*16 + (lane&15);
        bfv[ni] = *(const s16x8*)(bufc + row*128 + (colb ^ ((row&7)<<4)));
      }
      #pragma unroll
      for (int ni = 0; ni < 8; ++ni){
        acc[0][ni] = mfma16(af0, bfv[ni], acc[0][ni]);
        acc[1][ni] = mfma16(af1, bfv[ni], acc[1][ni]);
      }
    }
    __builtin_amdgcn_sched_barrier(0);   // keep reads above the WAR barrier
    __builtin_amdgcn_s_barrier();        // buf[t] free for stage(t+2)
  }
  __syncthreads();
  // hid = relu(G + pa_div + b1d) -> Bs buf0 as [64 pair-rows][256], 512B rows
  #pragma unroll
  for (int mi = 0; mi < 2; ++mi){
    #pragma unroll
    for (int ni = 0; ni < 8; ++ni){
      const int col = wc*128 + ni*16 + (lane&15);
      const float pav = P2[(size_t)(i0 + wm*2 + mi)*2304 + 1536 + n0 + col];
      #pragma unroll
      for (int r = 0; r < 4; ++r){
        const int row = wm*32 + mi*16 + (lane>>4)*4 + r;
        const float v = fmaxf(acc[mi][ni][r] + pav, 0.f);
        *(short*)((char*)Bs + row*512 + ((col*2) ^ ((row&7)<<4))) =
            (short)(__float_as_uint(v) >> 16);
      }
    }
  }
  __syncthreads();
  // logits partial (64 pair-rows x 16), K=256; w2 frags straight from global
  f32x4 acc2 = {0.f,0.f,0.f,0.f};
  const int arow = wv*16 + (lane&15);
  #pragma unroll
  for (int q = 0; q < 8; ++q){
    const int colb = (q*32 + (lane>>4)*8)*2;
    s16x8 a = *(const s16x8*)((const char*)Bs + arow*512 + (colb ^ ((arow&7)<<4)));
    s16x8 w = *(const s16x8*)(w2d_g + (size_t)(lane&15)*768 + n0 + q*32 + (lane>>4)*8);
    acc2 = mfma16(a, w, acc2);
  }
  const int r_ = lane & 15;
  #pragma unroll
  for (int r = 0; r < 4; ++r){
    const int p = wv*16 + (lane>>4)*4 + r;
    const int i = i0 + (p>>4), j = j0 + (p&15);
    Ldp[(size_t)nt*1048576 + (((size_t)i<<8) + j)*16 + r_] = acc2[r];
  }
}

// ---------------------------------------------------------------------------
// simpart: sim logits (final). Grid 544 triangle blocks, nt-loop in-block.
// ---------------------------------------------------------------------------
__global__ __launch_bounds__(256) void simpart(
    const float* __restrict__ P2,
    const short* __restrict__ w2s_g,
    float* __restrict__ Ls)            // [256][256][16] f32
{
  __shared__ short Hs[64*256];         // 32KB
  const int tid = threadIdx.x, lane = tid & 63, wv = tid >> 6;
  int i0, j0; tri_decode(blockIdx.x, i0, j0);
  const int arow = wv*16 + (lane&15);
  f32x4 acc2 = {0.f,0.f,0.f,0.f};
  for (int nt = 0; nt < 3; ++nt){
    const int n0 = nt*256;
    if (nt) __syncthreads();
    {
      const int row = tid>>2, c0 = (tid&3)*64;
      const float* pap = P2 + (size_t)(i0 + (row>>4))*2304 + n0 + c0;
      const float* pbp = P2 + (size_t)(j0 + (row&15))*2304 + 768 + n0 + c0;
      #pragma unroll
      for (int cc = 0; cc < 64; cc += 8){
        float4 a0 = *(const float4*)(pap+cc), a1 = *(const float4*)(pap+cc+4);
        float4 q0 = *(const float4*)(pbp+cc), q1 = *(const float4*)(pbp+cc+4);
        uint4 o;
        o.x = pack2bf(fmaxf(a0.x+q0.x,0.f), fmaxf(a0.y+q0.y,0.f));
        o.y = pack2bf(fmaxf(a0.z+q0.z,0.f), fmaxf(a0.w+q0.w,0.f));
        o.z = pack2bf(fmaxf(a1.x+q1.x,0.f), fmaxf(a1.y+q1.y,0.f));
        o.w = pack2bf(fmaxf(a1.z+q1.z,0.f), fmaxf(a1.w+q1.w,0.f));
        *(uint4*)((char*)Hs + row*512 + (((c0+cc)*2) ^ ((row&7)<<4))) = o;
      }
    }
    __syncthreads();
    #pragma unroll
    for (int q = 0; q < 8; ++q){
      const int colb = (q*32 + (lane>>4)*8)*2;
      s16x8 a = *(const s16x8*)((const char*)Hs + arow*512 + (colb ^ ((arow&7)<<4)));
      s16x8 w = *(const s16x8*)(w2s_g + (size_t)(lane&15)*768 + n0 + q*32 + (lane>>4)*8);
      acc2 = mfma16(a, w, acc2);
    }
  }
  const int r_ = lane & 15;
  #pragma unroll
  for (int r = 0; r < 4; ++r){
    const int p = wv*16 + (lane>>4)*4 + r;
    const int i = i0 + (p>>4), j = j0 + (p&15);
    Ls[(((size_t)i<<8) + j)*16 + r_] = acc2[r];
  }
}

// ---------------------------------------------------------------------------
// finisher: sum div partials, +b2, softmax both, symmetrize, write sim/div/C
// ---------------------------------------------------------------------------
__global__ __launch_bounds__(256) void finisher2(
    const float* __restrict__ Ls, const float* __restrict__ Ldp,
    const float* __restrict__ b2s, const float* __restrict__ b2d,
    float* __restrict__ simo, float* __restrict__ divo, short* __restrict__ Cb)
{
  const int p = blockIdx.x*256 + threadIdx.x;
  const int i = p >> 8, j = p & 255;
  float so[16], dd[16];
  if (i == j){
    #pragma unroll
    for (int r = 0; r < 16; ++r){ so[r] = 0.f; dd[r] = 0.f; }
  } else {
    const int si = i < j ? i : j, sj = i < j ? j : i;
    const size_t base = (((size_t)si << 8) + sj) * 16;
    float mx = -1e30f, sum;
    #pragma unroll
    for (int r = 0; r < 16; ++r){ so[r] = Ls[base+r] + b2s[r]; mx = fmaxf(mx, so[r]); }
    sum = 0.f;
    #pragma unroll
    for (int r = 0; r < 16; ++r){ so[r] = expf(so[r]-mx); sum += so[r]; }
    sum = 1.f/sum;
    #pragma unroll
    for (int r = 0; r < 16; ++r) so[r] *= sum;
    mx = -1e30f;
    #pragma unroll
    for (int r = 0; r < 16; ++r){
      dd[r] = Ldp[base+r] + Ldp[base+r+1048576] + Ldp[base+r+2097152] + b2d[r];
      mx = fmaxf(mx, dd[r]);
    }
    sum = 0.f;
    #pragma unroll
    for (int r = 0; r < 16; ++r){ dd[r] = expf(dd[r]-mx); sum += dd[r]; }
    sum = 1.f/sum;
    #pragma unroll
    for (int r = 0; r < 16; ++r) dd[r] *= sum;
  }
  const size_t ob = (size_t)p * 16;
  #pragma unroll
  for (int r = 0; r < 16; ++r){
    simo[ob+r] = so[r];
    divo[ob+r] = dd[r];
    Cb[ob+r]   = f2bf_s(0.5f*(so[r]+dd[r]));
  }
}

// ---------------------------------------------------------------------------
// T GEMM, BM=128, 256 thr, fused rel_w f32->bf16. Grid 384 (= 2 mt x 192 nt).
// ---------------------------------------------------------------------------
__global__ __launch_bounds__(256) void gemm_relT(
    const short* __restrict__ A,     // COMB, lda=1536
    const float* __restrict__ Bf,    // 12288 x 768 f32
    short* __restrict__ T,           // 256 x 12288 bf16
    const float* __restrict__ bias)  // 12288
{
  __shared__ short As[128*64];   // 16KB, 128B rows
  __shared__ short Bs[64*64];    // 8KB
  const int tid = threadIdx.x, lane = tid & 63, wv = tid >> 6;
  const int nt = blockIdx.x >> 1, mt = blockIdx.x & 1;
  const int n0 = nt*64, m0 = mt*128;
  const int wm = wv >> 1, wn = wv & 1;
  const int brow = tid >> 2, q4 = tid & 3;
  f32x4 acc[4][2] = {};
  for (int k0 = 0; k0 < 768; k0 += 64){
    if (k0) __syncthreads();
    #pragma unroll
    for (int q = 0; q < 4; ++q){
      const int d = (wv*4+q)*1024 + lane*16;
      const int row = d>>7, c = d&127;
      gload16((char*)As + (wv*4+q)*1024,
              (const char*)A + (size_t)(m0+row)*3072 + (size_t)k0*2 + (c ^ ((row&7)<<4)));
    }
    {
      const float* bp = Bf + (size_t)(n0+brow)*768 + k0 + q4*16;
      float4 v0 = *(const float4*)bp,      v1 = *(const float4*)(bp+4);
      float4 v2 = *(const float4*)(bp+8),  v3 = *(const float4*)(bp+12);
      union { uint4 v; unsigned u[4]; } ua, ub;
      ua.u[0]=pack2bf(v0.x,v0.y); ua.u[1]=pack2bf(v0.z,v0.w);
      ua.u[2]=pack2bf(v1.x,v1.y); ua.u[3]=pack2bf(v1.z,v1.w);
      ub.u[0]=pack2bf(v2.x,v2.y); ub.u[1]=pack2bf(v2.z,v2.w);
      ub.u[2]=pack2bf(v3.x,v3.y); ub.u[3]=pack2bf(v3.z,v3.w);
      const int bc = q4*32;
      *(uint4*)((char*)Bs + brow*128 + ((bc   ) ^ ((brow&7)<<4))) = ua.v;
      *(uint4*)((char*)Bs + brow*128 + ((bc+16) ^ ((brow&7)<<4))) = ub.v;
    }
    __syncthreads();
    #pragma unroll
    for (int kk = 0; kk < 2; ++kk){
      const int kb = kk*64 + (lane>>4)*16;
      s16x8 af[4], bfv[2];
      #pragma unroll
      for (int mi = 0; mi < 4; ++mi){
        const int row = wm*64 + mi*16 + (lane&15);
        af[mi] = *(const s16x8*)((char*)As + row*128 + (kb ^ ((row&7)<<4)));
      }
      #pragma unroll
      for (int ni = 0; ni < 2; ++ni){
        const int row = wn*32 + ni*16 + (lane&15);
        bfv[ni] = *(const s16x8*)((char*)Bs + row*128 + (kb ^ ((row&7)<<4)));
      }
      #pragma unroll
      for (int mi = 0; mi < 4; ++mi)
        #pragma unroll
        for (int ni = 0; ni < 2; ++ni)
          acc[mi][ni] = mfma16(af[mi], bfv[ni], acc[mi][ni]);
    }
  }
  #pragma unroll
  for (int mi = 0; mi < 4; ++mi)
    #pragma unroll
    for (int ni = 0; ni < 2; ++ni){
      const int nn = n0 + wn*32 + ni*16 + (lane&15);
      const float bv = bias[nn];
      #pragma unroll
      for (int r = 0; r < 4; ++r){
        const int row = m0 + wm*64 + mi*16 + (lane>>4)*4 + r;
        T[(size_t)row*12288 + nn] = f2bf_s(acc[mi][ni][r] + bv);
      }
    }
}

// ---------------------------------------------------------------------------
// LayerNorm(y + x) -> x (f32), comb[:, :768] (bf16), optional d_out x
// ---------------------------------------------------------------------------
__global__ __launch_bounds__(256) void ln_kernel(
    const float* __restrict__ y, float* __restrict__ x, short* __restrict__ combx,
    const float* __restrict__ g, const float* __restrict__ b, float* __restrict__ xfinal)
{
  const int row = blockIdx.x, tid = threadIdx.x;
  float tv[3]; float s = 0.f, s2 = 0.f;
  #pragma unroll
  for (int c = 0; c < 3; ++c){
    const int idx = tid + c*256;
    const float v = y[row*768+idx] + x[row*768+idx];
    tv[c] = v; s += v; s2 += v*v;
  }
  #pragma unroll
  for (int off = 32; off > 0; off >>= 1){ s += __shfl_down(s, off); s2 += __shfl_down(s2, off); }
  __shared__ float red[8];
  const int wid = tid >> 6, lane = tid & 63;
  if (lane == 0){ red[wid] = s; red[wid+4] = s2; }
  __syncthreads();
  if (tid == 0){
    red[0] = red[0]+red[1]+red[2]+red[3];
    red[4] = red[4]+red[5]+red[6]+red[7];
  }
  __syncthreads();
  const float mu = red[0]*(1.f/768.f);
  const float var = red[4]*(1.f/768.f) - mu*mu;
  const float inv = rsqrtf(var + 1e-5f);
  #pragma unroll
  for (int c = 0; c < 3; ++c){
    const int idx = tid + c*256;
    const float v = (tv[c]-mu)*inv*g[idx] + b[idx];
    x[row*768+idx] = v;
    combx[(size_t)row*1536 + idx] = f2bf_s(v);
    if (xfinal) xfinal[row*768+idx] = v;
  }
}

// ---------------------------------------------------------------------------
// setup_all: every f32->bf16 weight conversion + concat + bias concat, one
// kernel, block-range dispatch. 7993 blocks x 256 thr.
// ---------------------------------------------------------------------------
__device__ __forceinline__ void cvt4(const float* __restrict__ s,
                                     short* __restrict__ d, int i, int n){
  if (i >= n) return;
  float4 v = *(const float4*)(s+i);
  union { uint2 u; short s4[4]; } o;
  o.s4[0]=f2bf_s(v.x); o.s4[1]=f2bf_s(v.y); o.s4[2]=f2bf_s(v.z); o.s4[3]=f2bf_s(v.w);
  *(uint2*)(d+i) = o.u;
}

__global__ void setup_all(
    const float* __restrict__ sim_w2, const float* __restrict__ div_w2,
    const float* __restrict__ agg_w1, const float* __restrict__ agg_w2,
    const float* __restrict__ cls_w1, const float* __restrict__ sim_w1,
    const float* __restrict__ div_w1, const float* __restrict__ sup,
    const float* __restrict__ qry, const float* __restrict__ sim_b1,
    const float* __restrict__ div_b1,
    short* __restrict__ W2S, short* __restrict__ W2D, short* __restrict__ AW1,
    short* __restrict__ AW2, short* __restrict__ CW1, short* __restrict__ W1X4,
    float* __restrict__ XF, short* __restrict__ COMB, float* __restrict__ B1C)
{
  const int b = blockIdx.x, tid = threadIdx.x;
  if (b < 12)        cvt4(sim_w2, W2S, (b*256+tid)*4, 12288);
  else if (b < 24)   cvt4(div_w2, W2D, ((b-12)*256+tid)*4, 12288);
  else if (b < 3480) cvt4(agg_w1, AW1, ((b-24)*256+tid)*4, 3538944);
  else if (b < 5208) cvt4(agg_w2, AW2, ((b-3480)*256+tid)*4, 1769472);
  else if (b < 5496) cvt4(cls_w1, CW1, ((b-5208)*256+tid)*4, 294912);
  else if (b < 7800){                        // W1X4: {wa_s, wb_s, wa_d, wb_d}
    const int i = ((b-5496)*256+tid)*4;
    if (i < 2359296){
      const int mat = i / 589824, rem = i % 589824;
      const int r = rem / 768, c = rem % 768;
      const float* src = (mat < 2 ? sim_w1 : div_w1) + (size_t)r*1536 + (mat&1)*768 + c;
      float4 v = *(const float4*)src;
      union { uint2 u; short s4[4]; } o;
      o.s4[0]=f2bf_s(v.x); o.s4[1]=f2bf_s(v.y); o.s4[2]=f2bf_s(v.z); o.s4[3]=f2bf_s(v.w);
      *(uint2*)(W1X4+i) = o.u;
    }
  } else if (b < 7992){                      // concat x -> XF f32 + COMB bf16
    const int i = ((b-7800)*256+tid)*4;
    if (i < 196608){
      const int row = i / 768, col = i % 768;
      const float* s = (row < 128 ? sup + (size_t)row*768 : qry + (size_t)(row-128)*768) + col;
      float4 v = *(const float4*)s;
      *(float4*)(XF+i) = v;
      union { uint2 u; short s4[4]; } o;
      o.s4[0]=f2bf_s(v.x); o.s4[1]=f2bf_s(v.y); o.s4[2]=f2bf_s(v.z); o.s4[3]=f2bf_s(v.w);
      *(uint2*)(COMB + (size_t)row*1536 + col) = o.u;
    }
  } else {                                   // B1C = [b1s | 0 | b1d]
    for (int t = tid; t < 2304; t += 256)
      B1C[t] = (t < 768) ? sim_b1[t] : ((t < 1536) ? 0.f : div_b1[t-1536]);
  }
}

__global__ void cls2_kernel(const short* __restrict__ hc, const float* __restrict__ w2,
                            const float* __restrict__ b2, float* __restrict__ preds){
  const int t = blockIdx.x*192 + threadIdx.x;
  if (t >= 384) return;
  const int m = t/3, c = t - m*3;
  float s = b2[c];
  for (int k = 0; k < 384; ++k)
    s += bf_s2f(hc[m*384+k]) * w2[c*384+k];
  preds[m*3+c] = s;
}

// ---------------------------------------------------------------------------
// workspace layout (bytes, total ~52.7 MB)
// ---------------------------------------------------------------------------
static const size_t OFF_B1CAT = 0;          // 9216
static const size_t OFF_LS    = 16384;      // 4194304
static const size_t OFF_MSGF  = 4210688;    // 6291456  (8 slabs x 196608 f32)
static const size_t OFF_LDP   = 10502144;   // 12582912 (3 slabs)
static const size_t OFF_P     = 23085056;   // 2359296
static const size_t OFF_XF    = 25444352;   // 786432
static const size_t OFF_Y     = 26230784;   // 786432
static const size_t OFF_COMB  = 27017216;   // 786432
static const size_t OFF_CB    = 27803648;   // 2097152
static const size_t OFF_W1X4  = 29900800;   // 4718592
static const size_t OFF_W2S   = 34619392;   // 24576
static const size_t OFF_W2D   = 34643968;   // 24576
static const size_t OFF_AW1   = 34668544;   // 7077888
static const size_t OFF_AW2   = 41746432;   // 3538944
static const size_t OFF_CW1   = 45285376;   // 589824
static const size_t OFF_TBUF  = 45875200;   // 6291456
static const size_t OFF_HID1  = 52166656;   // 393216
static const size_t OFF_HIDC  = 52559872;   // 98304

extern "C" void kernel_launch(void* const* d_in, const int* in_sizes, int n_in,
                              void* d_out, int out_size, void* d_ws, size_t ws_size,
                              hipStream_t stream)
{
  (void)in_sizes; (void)n_in; (void)out_size; (void)ws_size;
  const float* sup    = (const float*)d_in[0];
  const float* qry    = (const float*)d_in[2];
  const float* sim_w1 = (const float*)d_in[3];
  const float* sim_b1 = (const float*)d_in[4];
  const float* sim_w2 = (const float*)d_in[5];
  const float* sim_b2 = (const float*)d_in[6];
  const float* div_w1 = (const float*)d_in[7];
  const float* div_b1 = (const float*)d_in[8];
  const float* div_w2 = (const float*)d_in[9];
  const float* div_b2 = (const float*)d_in[10];
  const float* rel_w  = (const float*)d_in[11];
  const float* rel_b  = (const float*)d_in[12];
  const float* agg_w1 = (const float*)d_in[13];
  const float* agg_b1 = (const float*)d_in[14];
  const float* agg_w2 = (const float*)d_in[15];
  const float* agg_b2 = (const float*)d_in[16];
  const float* ln_g   = (const float*)d_in[17];
  const float* ln_b   = (const float*)d_in[18];
  const float* cls_w1 = (const float*)d_in[19];
  const float* cls_b1 = (const float*)d_in[20];
  const float* cls_w2 = (const float*)d_in[21];
  const float* cls_b2 = (const float*)d_in[22];

  char* w = (char*)d_ws;
  float* B1C  = (float*)(w + OFF_B1CAT);
  float* LS   = (float*)(w + OFF_LS);
  float* MSGF = (float*)(w + OFF_MSGF);
  float* LDP  = (float*)(w + OFF_LDP);
  float* P2   = (float*)(w + OFF_P);
  float* XF   = (float*)(w + OFF_XF);
  float* Y    = (float*)(w + OFF_Y);
  short* COMB = (short*)(w + OFF_COMB);
  short* CB   = (short*)(w + OFF_CB);
  short* W1X4 = (short*)(w + OFF_W1X4);
  short* W2S  = (short*)(w + OFF_W2S);
  short* W2D  = (short*)(w + OFF_W2D);
  short* AW1  = (short*)(w + OFF_AW1);
  short* AW2  = (short*)(w + OFF_AW2);
  short* CW1  = (short*)(w + OFF_CW1);
  short* TBUF = (short*)(w + OFF_TBUF);
  short* HID1 = (short*)(w + OFF_HID1);
  short* HIDC = (short*)(w + OFF_HIDC);

  float* preds = (float*)d_out;
  float* simo  = preds + 384;
  float* divo  = simo + 1048576;
  float* xout  = divo + 1048576;

  // all setup in one kernel
  setup_all<<<7993, 256, 0, stream>>>(sim_w2, div_w2, agg_w1, agg_w2, cls_w1,
                                      sim_w1, div_w1, sup, qry, sim_b1, div_b1,
                                      W2S, W2D, AW1, AW2, CW1, W1X4, XF, COMB, B1C);

  // P2 = x @ [wa_s|wb_s|wa_d]^T + [b1s|0|b1d]   (M=256,N=2304,K=768)
  gemm_bt2<64,64,3><<<144, 256, 0, stream>>>(COMB, 1536, W1X4, 768, P2, nullptr, 2304,
                                             B1C, 768, 36);

  // relations
  pairrel3<<<dim3(544,3), 256, 0, stream>>>(COMB, W1X4 + (size_t)3*589824, P2, W2D, LDP);
  simpart<<<544, 256, 0, stream>>>(P2, W2S, LS);
  finisher2<<<256, 256, 0, stream>>>(LS, LDP, sim_b2, div_b2, simo, divo, CB);

  for (int l = 0; l < 3; ++l){
    gemm_relT<<<384, 256, 0, stream>>>(COMB, rel_w + (size_t)l*9437184, TBUF,
                                       rel_b + l*12288);
    gemm_msg<<<dim3(48,8), 256, 0, stream>>>(CB, TBUF, MSGF);
    msgsum<<<192, 256, 0, stream>>>(MSGF, COMB);
    gemm_bt2<32,32,2><<<192, 256, 0, stream>>>(COMB, 1536, AW1 + (size_t)l*1179648, 1536,
                                               nullptr, HID1, 768, agg_b1 + l*768, 1536, 24);
    gemm_bt2<32,32,3><<<192, 256, 0, stream>>>(HID1, 768, AW2 + (size_t)l*589824, 768,
                                               Y, nullptr, 768, agg_b2 + l*768, 768, 24);
    ln_kernel<<<256, 256, 0, stream>>>(Y, XF, COMB, ln_g + l*768, ln_b + l*768,
                                       (l == 2) ? xout : nullptr);
  }

  gemm_bt2<32,32,2><<<48, 256, 0, stream>>>(COMB + (size_t)128*1536, 1536, CW1, 768,
                                            nullptr, HIDC, 384, cls_b1, 768, 12);
  cls2_kernel<<<2, 192, 0, stream>>>(HIDC, cls_w2, cls_b2, preds);
}

// Round 6
// 304.869 us; speedup vs baseline: 1.9812x; 1.0520x over previous
//
#include <hip/hip_runtime.h>
#include <hip/hip_bf16.h>

// ---------------------------------------------------------------------------
// DualRelationsPropagation on MI355X (gfx950) — round 6
// vs r5: pairrel4 = 4i x 32j blocks (288x3 grid, 512 thr, 8 waves), 64KB LDS
// double-buffer with CORRECT counted-vmcnt order (x loads issued before
// stage(t+1), so stage stays in flight across compute). B staging traffic
// halved vs r4. Everything else kept from r5 (which gained 37us).
// ---------------------------------------------------------------------------

typedef __attribute__((ext_vector_type(8))) short s16x8;
typedef __attribute__((ext_vector_type(4))) float f32x4;

__device__ __forceinline__ short f2bf_s(float f){
  union { __hip_bfloat16 h; short s; } u; u.h = __float2bfloat16(f); return u.s;
}
__device__ __forceinline__ float bf_s2f(short s){
  union { __hip_bfloat16 h; short s; } u; u.s = s; return __bfloat162float(u.h);
}
__device__ __forceinline__ f32x4 mfma16(s16x8 a, s16x8 b, f32x4 c){
  return __builtin_amdgcn_mfma_f32_16x16x32_bf16(a, b, c, 0, 0, 0);
}
__device__ __forceinline__ void gload16(void* lds, const void* g){
  __builtin_amdgcn_global_load_lds((const __attribute__((address_space(1))) void*)g,
                                   (__attribute__((address_space(3))) void*)lds,
                                   16, 0, 0);
}
__device__ __forceinline__ unsigned pack2bf(float lo, float hi){
  return __builtin_amdgcn_perm(__float_as_uint(hi), __float_as_uint(lo), 0x07060302u);
}
// |a-b| on 8 packed bf16: unpack, sub, cvt_pk with abs input modifiers (RNE)
__device__ __forceinline__ s16x8 absdiff_bf(uint4 a, uint4 b){
  union { s16x8 v; unsigned u[4]; } o;
  const unsigned au[4] = {a.x,a.y,a.z,a.w}, bu[4] = {b.x,b.y,b.z,b.w};
  #pragma unroll
  for (int w = 0; w < 4; ++w){
    float dlo = __uint_as_float(au[w] << 16)         - __uint_as_float(bu[w] << 16);
    float dhi = __uint_as_float(au[w] & 0xffff0000u) - __uint_as_float(bu[w] & 0xffff0000u);
    unsigned r;
    asm("v_cvt_pk_bf16_f32 %0, abs(%1), abs(%2)" : "=v"(r) : "v"(dlo), "v"(dhi));
    o.u[w] = r;
  }
  return o.v;
}

// triangle decode, 4i x 16j tiles (for simpart): start(jb) = 2jb(jb+1)
__device__ __forceinline__ void tri_decode(int b, int& i0, int& j0){
  int jb = (int)((sqrtf(2.f*(float)b + 1.f) - 1.f)*0.5f);
  while (2*(jb+1)*(jb+2) <= b) ++jb;
  while (2*jb*(jb+1) > b) --jb;
  i0 = (b - 2*jb*(jb+1))*4;
  j0 = jb*16;
}
// triangle decode, 4i x 32j tiles (for pairrel4): start(jb) = 4jb(jb+1)
__device__ __forceinline__ void tri_decode32(int b, int& i0, int& j0){
  int jb = (int)((sqrtf((float)b + 1.f) - 1.f)*0.5f);
  while (4*(jb+1)*(jb+2) <= b) ++jb;
  while (4*jb*(jb+1) > b) --jb;
  i0 = (b - 4*jb*(jb+1))*4;
  j0 = jb*32;
}

// ---------------------------------------------------------------------------
// Generic bf16 GEMM, BK=128: C(MxN) = A(MxK) * B^T (B stored N x K row-major).
// 256 thr = 4 waves 2x2. A,B staged via global_load_lds (swizzled source).
// EPI: 2 = relu(+bias) -> bf16, 3 = +bias -> f32
// ---------------------------------------------------------------------------
template<int BM, int BN, int EPI>
__global__ __launch_bounds__(256) void gemm_bt2(
    const short* __restrict__ A, int lda,
    const short* __restrict__ B, int ldb,
    float* __restrict__ Cf, short* __restrict__ Cb, int ldc,
    const float* __restrict__ bias, int K, int NT)
{
  __shared__ short As[BM*128];   // 256B rows
  __shared__ short Bs[BN*128];
  const int tid = threadIdx.x, lane = tid & 63, wid = tid >> 6;
  const int nt = blockIdx.x % NT, mt = blockIdx.x / NT;
  const int m0 = mt*BM, n0 = nt*BN;
  const int wm0 = (wid>>1)*(BM/2), wn0 = (wid&1)*(BN/2);
  f32x4 acc[BM/32][BN/32] = {};
  for (int k0 = 0; k0 < K; k0 += 128){
    if (k0) __syncthreads();
    #pragma unroll
    for (int q = 0; q < BM/16; ++q){
      const int d = (wid*(BM/16)+q)*1024 + lane*16;
      const int row = d>>8, c = d&255;
      gload16((char*)As + (wid*(BM/16)+q)*1024,
              (const char*)A + (size_t)(m0+row)*lda*2 + (size_t)k0*2 + (c ^ ((row&7)<<4)));
    }
    #pragma unroll
    for (int q = 0; q < BN/16; ++q){
      const int d = (wid*(BN/16)+q)*1024 + lane*16;
      const int row = d>>8, c = d&255;
      gload16((char*)Bs + (wid*(BN/16)+q)*1024,
              (const char*)B + (size_t)(n0+row)*ldb*2 + (size_t)k0*2 + (c ^ ((row&7)<<4)));
    }
    __syncthreads();
    #pragma unroll
    for (int kk = 0; kk < 4; ++kk){
      const int colb = (kk*32 + (lane>>4)*8)*2;
      s16x8 af[BM/32], bfv[BN/32];
      #pragma unroll
      for (int mi = 0; mi < BM/32; ++mi){
        const int row = wm0 + mi*16 + (lane&15);
        af[mi] = *(const s16x8*)((char*)As + row*256 + (colb ^ ((row&7)<<4)));
      }
      #pragma unroll
      for (int ni = 0; ni < BN/32; ++ni){
        const int row = wn0 + ni*16 + (lane&15);
        bfv[ni] = *(const s16x8*)((char*)Bs + row*256 + (colb ^ ((row&7)<<4)));
      }
      #pragma unroll
      for (int mi = 0; mi < BM/32; ++mi)
        #pragma unroll
        for (int ni = 0; ni < BN/32; ++ni)
          acc[mi][ni] = mfma16(af[mi], bfv[ni], acc[mi][ni]);
    }
  }
  #pragma unroll
  for (int mi = 0; mi < BM/32; ++mi){
    #pragma unroll
    for (int ni = 0; ni < BN/32; ++ni){
      const int gcol = n0 + wn0 + ni*16 + (lane&15);
      const float bv = bias[gcol];
      #pragma unroll
      for (int r = 0; r < 4; ++r){
        const int grow = m0 + wm0 + mi*16 + (lane>>4)*4 + r;
        float v = acc[mi][ni][r] + bv;
        if (EPI == 2) v = fmaxf(v, 0.f);
        if (EPI == 3) Cf[(size_t)grow*ldc + gcol] = v;
        else          Cb[(size_t)grow*ldc + gcol] = f2bf_s(v);
      }
    }
  }
}

// ---------------------------------------------------------------------------
// msg GEMM, split-K slabs: slab[kc] = CB(256 x 512-chunk) * TBUF(chunk x 768).
// grid (48, 8): 64x64 tile. Plain stores (no atomics, no memset).
// ---------------------------------------------------------------------------
__global__ __launch_bounds__(256) void gemm_msg(
    const short* __restrict__ A,    // CB, lda 4096
    const short* __restrict__ B,    // TBUF as (4096 x 768) K-major
    float* __restrict__ slabs)
{
  __shared__ short As[64*64];      // 128B rows
  __shared__ short Bs[64*64];      // transposed: [n][k]
  const int tid = threadIdx.x, lane = tid & 63, wid = tid >> 6;
  const int mt = blockIdx.x / 12, nt = blockIdx.x % 12;
  const int m0 = mt*64, n0 = nt*64, kc0 = blockIdx.y*512;
  const int wm0 = (wid>>1)*32, wn0 = (wid&1)*32;
  f32x4 acc[2][2] = {};
  for (int s = 0; s < 8; ++s){
    const int k0 = kc0 + s*64;
    if (s) __syncthreads();
    #pragma unroll
    for (int q = 0; q < 2; ++q){
      const int d = (wid*2+q)*1024 + lane*16;
      const int row = d>>7, c = d&127;
      gload16((char*)As + (wid*2+q)*1024,
              (const char*)A + (size_t)(m0+row)*8192 + (size_t)k0*2 + (c ^ ((row&7)<<4)));
    }
    #pragma unroll
    for (int rd = 0; rd < 2; ++rd){
      int ei = rd*2048 + tid*8, kr = ei>>6, nc = ei&63;
      union { uint4 v; short s4[8]; } u;
      u.v = *(const uint4*)(B + (size_t)(k0+kr)*768 + n0 + nc);
      #pragma unroll
      for (int e = 0; e < 8; ++e)
        *(short*)((char*)Bs + (nc+e)*128 + ((kr*2) ^ (((nc+e)&7)<<4))) = u.s4[e];
    }
    __syncthreads();
    #pragma unroll
    for (int kk = 0; kk < 2; ++kk){
      const int colb = (kk*32 + (lane>>4)*8)*2;
      s16x8 af[2], bfv[2];
      #pragma unroll
      for (int mi = 0; mi < 2; ++mi){
        const int row = wm0 + mi*16 + (lane&15);
        af[mi] = *(const s16x8*)((char*)As + row*128 + (colb ^ ((row&7)<<4)));
      }
      #pragma unroll
      for (int ni = 0; ni < 2; ++ni){
        const int row = wn0 + ni*16 + (lane&15);
        bfv[ni] = *(const s16x8*)((char*)Bs + row*128 + (colb ^ ((row&7)<<4)));
      }
      #pragma unroll
      for (int mi = 0; mi < 2; ++mi)
        #pragma unroll
        for (int ni = 0; ni < 2; ++ni)
          acc[mi][ni] = mfma16(af[mi], bfv[ni], acc[mi][ni]);
    }
  }
  float* out = slabs + (size_t)blockIdx.y*196608;
  #pragma unroll
  for (int mi = 0; mi < 2; ++mi)
    #pragma unroll
    for (int ni = 0; ni < 2; ++ni){
      const int gcol = n0 + wn0 + ni*16 + (lane&15);
      #pragma unroll
      for (int r = 0; r < 4; ++r){
        const int grow = m0 + wm0 + mi*16 + (lane>>4)*4 + r;
        out[(size_t)grow*768 + gcol] = acc[mi][ni][r];
      }
    }
}

// sum 8 slabs, *1/255, cvt bf16 -> comb[:, 768:1536]
__global__ void msgsum(const float* __restrict__ slabs, short* __restrict__ comb){
  const int i = (blockIdx.x*256 + threadIdx.x)*4;
  if (i >= 196608) return;
  float4 s = {0.f,0.f,0.f,0.f};
  #pragma unroll
  for (int c = 0; c < 8; ++c){
    float4 v = *(const float4*)(slabs + (size_t)c*196608 + i);
    s.x += v.x; s.y += v.y; s.z += v.z; s.w += v.w;
  }
  const float sc = 1.f/255.f;
  const int row = i/768, col = i%768;
  union { uint2 u; short s4[4]; } o;
  o.s4[0]=f2bf_s(s.x*sc); o.s4[1]=f2bf_s(s.y*sc);
  o.s4[2]=f2bf_s(s.z*sc); o.s4[3]=f2bf_s(s.w*sc);
  *(uint2*)(comb + (size_t)row*1536 + 768 + col) = o.u;
}

// ---------------------------------------------------------------------------
// pairrel4: div-relation partial logits. Grid dim3(288,3): triangle block of
// 4 i x 32 j (128 pair rows), nt = 256-col chunk. 512 thr = 8 waves
// (ip x jj x wc). 64KB LDS double-buffered B, counted-vmcnt pipeline with
// x-loads issued FIRST (so stage(t+1) stays in flight through compute).
// Epilogue: 2 rounds of 64-row hid -> logits MFMA (K split over 8 waves,
// LDS partial-reduce) -> Ldp slab per nt.
// ---------------------------------------------------------------------------
__global__ __launch_bounds__(512, 4) void pairrel4(
    const short* __restrict__ xb,      // COMB, x cols [0,768), stride 1536
    const short* __restrict__ wbdiv,   // 768x768 bf16 (B^T layout)
    const float* __restrict__ P2,      // 256x2304: [pa_s+b1s | pb_s | pa_d+b1d]
    const short* __restrict__ w2d_g,   // 16x768 bf16
    float* __restrict__ Ldp)           // [3][256][256][16] f32 partials
{
  __shared__ short Bs[2*256*64];       // 64KB dbuf; buf0 reused as hid, buf1 as reduce
  const int tid = threadIdx.x, lane = tid & 63, wv = tid >> 6;
  const int ip = wv >> 2, jj = (wv >> 1) & 1, wc = wv & 1;
  int i0, j0; tri_decode32(blockIdx.x, i0, j0);
  const int nt = blockIdx.y, n0 = nt*256;

  const short* xjp  = xb + (size_t)(j0 + jj*16 + (lane&15))*1536 + (lane>>4)*8;
  const short* xi0p = xb + (size_t)(i0 + 2*ip    )*1536 + (lane>>4)*8;
  const short* xi1p = xb + (size_t)(i0 + 2*ip + 1)*1536 + (lane>>4)*8;

  // prologue: stage buf0 (k0 = 0)
  #pragma unroll
  for (int q = 0; q < 4; ++q){
    const int d = (wv*4+q)*1024 + lane*16;
    const int row = d>>7, c = d&127;
    gload16((char*)Bs + (wv*4+q)*1024,
            (const char*)wbdiv + (size_t)(n0+row)*1536 + (c ^ ((row&7)<<4)));
  }

  f32x4 acc[2][8] = {};
  for (int t = 0; t < 12; ++t){
    // x loads FIRST (older than next stage -> compiler's x-wait leaves stage flying)
    uint4 uja  = *(const uint4*)(xjp  + t*64);
    uint4 ujb  = *(const uint4*)(xjp  + t*64 + 32);
    uint4 ui0a = *(const uint4*)(xi0p + t*64);
    uint4 ui0b = *(const uint4*)(xi0p + t*64 + 32);
    uint4 ui1a = *(const uint4*)(xi1p + t*64);
    uint4 ui1b = *(const uint4*)(xi1p + t*64 + 32);
    if (t < 11){
      char* dst = (char*)Bs + ((t+1)&1)*32768;
      const char* src = (const char*)wbdiv + (size_t)(t+1)*128;
      #pragma unroll
      for (int q = 0; q < 4; ++q){
        const int d = (wv*4+q)*1024 + lane*16;
        const int row = d>>7, c = d&127;
        gload16(dst + (wv*4+q)*1024, src + (size_t)(n0+row)*1536 + (c ^ ((row&7)<<4)));
      }
    }
    __builtin_amdgcn_sched_barrier(0);
    // drain exactly own stage(t) (4 oldest); x(6)+stage(t+1)(4) stay in flight
    if (t < 11) asm volatile("s_waitcnt vmcnt(10)" ::: "memory");
    else        asm volatile("s_waitcnt vmcnt(6)"  ::: "memory");
    __builtin_amdgcn_s_barrier();        // all waves' stage(t) visible
    __builtin_amdgcn_sched_barrier(0);
    const char* bufc = (const char*)Bs + (t&1)*32768;
    #pragma unroll
    for (int kk = 0; kk < 2; ++kk){
      s16x8 af0 = absdiff_bf(kk ? ujb : uja, kk ? ui0b : ui0a);
      s16x8 af1 = absdiff_bf(kk ? ujb : uja, kk ? ui1b : ui1a);
      const int colb = (kk*32 + (lane>>4)*8)*2;
      #pragma unroll
      for (int ni = 0; ni < 8; ++ni){
        const int row = wc*128 + ni*16 + (lane&15);
        s16x8 bv = *(const s16x8*)(bufc + row*128 + (colb ^ ((row&7)<<4)));
        acc[0][ni] = mfma16(af0, bv, acc[0][ni]);
        acc[1][ni] = mfma16(af1, bv, acc[1][ni]);
      }
    }
    __builtin_amdgcn_sched_barrier(0);   // keep reads above the WAR barrier
    __builtin_amdgcn_s_barrier();        // buf[t&1] free for stage(t+2)
  }
  __syncthreads();

  // epilogue: two rounds of 64 pair-rows (p = i_local*32 + j_local)
  float* red = (float*)((char*)Bs + 32768);   // buf1 scratch: f32[64][16]
  #pragma unroll
  for (int h = 0; h < 2; ++h){
    if (ip == h){
      #pragma unroll
      for (int mi = 0; mi < 2; ++mi){
        const float* pr = P2 + (size_t)(i0 + 2*h + mi)*2304 + 1536 + n0;
        #pragma unroll
        for (int ni = 0; ni < 8; ++ni){
          const int col = wc*128 + ni*16 + (lane&15);
          const float pav = pr[col];
          #pragma unroll
          for (int r = 0; r < 4; ++r){
            const int lrow = mi*32 + jj*16 + (lane>>4)*4 + r;
            const float v = fmaxf(acc[mi][ni][r] + pav, 0.f);
            *(short*)((char*)Bs + lrow*512 + ((col*2) ^ ((lrow&7)<<4))) =
                (short)(__float_as_uint(v) >> 16);
          }
        }
      }
    }
    __syncthreads();
    // logits: 64 rows x 16, K=256 split across kh = wv>>2
    const int kh = wv >> 2, rq = wv & 3;
    f32x4 a2 = {0.f,0.f,0.f,0.f};
    const int arow = rq*16 + (lane&15);
    #pragma unroll
    for (int q = 0; q < 4; ++q){
      const int k = kh*128 + q*32 + (lane>>4)*8;
      s16x8 a = *(const s16x8*)((char*)Bs + arow*512 + ((k*2) ^ ((arow&7)<<4)));
      s16x8 w = *(const s16x8*)(w2d_g + (size_t)(lane&15)*768 + n0 + k);
      a2 = mfma16(a, w, a2);
    }
    if (kh == 1){
      #pragma unroll
      for (int r = 0; r < 4; ++r)
        red[(rq*16 + (lane>>4)*4 + r)*16 + (lane&15)] = a2[r];
    }
    __syncthreads();
    if (kh == 0){
      #pragma unroll
      for (int r = 0; r < 4; ++r){
        const int lrow = rq*16 + (lane>>4)*4 + r;
        const int p = h*64 + lrow;
        const int i = i0 + (p>>5), j = j0 + (p&31);
        Ldp[(size_t)nt*1048576 + (((size_t)i<<8) + j)*16 + (lane&15)]
          = a2[r] + red[lrow*16 + (lane&15)];
      }
    }
    __syncthreads();   // before round h=1 overwrites Bs/red
  }
}

// ---------------------------------------------------------------------------
// simpart: sim logits (final). Grid 544 triangle blocks, nt-loop in-block.
// ---------------------------------------------------------------------------
__global__ __launch_bounds__(256) void simpart(
    const float* __restrict__ P2,
    const short* __restrict__ w2s_g,
    float* __restrict__ Ls)            // [256][256][16] f32
{
  __shared__ short Hs[64*256];         // 32KB
  const int tid = threadIdx.x, lane = tid & 63, wv = tid >> 6;
  int i0, j0; tri_decode(blockIdx.x, i0, j0);
  const int arow = wv*16 + (lane&15);
  f32x4 acc2 = {0.f,0.f,0.f,0.f};
  for (int nt = 0; nt < 3; ++nt){
    const int n0 = nt*256;
    if (nt) __syncthreads();
    {
      const int row = tid>>2, c0 = (tid&3)*64;
      const float* pap = P2 + (size_t)(i0 + (row>>4))*2304 + n0 + c0;
      const float* pbp = P2 + (size_t)(j0 + (row&15))*2304 + 768 + n0 + c0;
      #pragma unroll
      for (int cc = 0; cc < 64; cc += 8){
        float4 a0 = *(const float4*)(pap+cc), a1 = *(const float4*)(pap+cc+4);
        float4 q0 = *(const float4*)(pbp+cc), q1 = *(const float4*)(pbp+cc+4);
        uint4 o;
        o.x = pack2bf(fmaxf(a0.x+q0.x,0.f), fmaxf(a0.y+q0.y,0.f));
        o.y = pack2bf(fmaxf(a0.z+q0.z,0.f), fmaxf(a0.w+q0.w,0.f));
        o.z = pack2bf(fmaxf(a1.x+q1.x,0.f), fmaxf(a1.y+q1.y,0.f));
        o.w = pack2bf(fmaxf(a1.z+q1.z,0.f), fmaxf(a1.w+q1.w,0.f));
        *(uint4*)((char*)Hs + row*512 + (((c0+cc)*2) ^ ((row&7)<<4))) = o;
      }
    }
    __syncthreads();
    #pragma unroll
    for (int q = 0; q < 8; ++q){
      const int colb = (q*32 + (lane>>4)*8)*2;
      s16x8 a = *(const s16x8*)((const char*)Hs + arow*512 + (colb ^ ((arow&7)<<4)));
      s16x8 w = *(const s16x8*)(w2s_g + (size_t)(lane&15)*768 + n0 + q*32 + (lane>>4)*8);
      acc2 = mfma16(a, w, acc2);
    }
  }
  const int r_ = lane & 15;
  #pragma unroll
  for (int r = 0; r < 4; ++r){
    const int p = wv*16 + (lane>>4)*4 + r;
    const int i = i0 + (p>>4), j = j0 + (p&15);
    Ls[(((size_t)i<<8) + j)*16 + r_] = acc2[r];
  }
}

// ---------------------------------------------------------------------------
// finisher: sum div partials, +b2, softmax both, symmetrize, write sim/div/C
// ---------------------------------------------------------------------------
__global__ __launch_bounds__(256) void finisher2(
    const float* __restrict__ Ls, const float* __restrict__ Ldp,
    const float* __restrict__ b2s, const float* __restrict__ b2d,
    float* __restrict__ simo, float* __restrict__ divo, short* __restrict__ Cb)
{
  const int p = blockIdx.x*256 + threadIdx.x;
  const int i = p >> 8, j = p & 255;
  float so[16], dd[16];
  if (i == j){
    #pragma unroll
    for (int r = 0; r < 16; ++r){ so[r] = 0.f; dd[r] = 0.f; }
  } else {
    const int si = i < j ? i : j, sj = i < j ? j : i;
    const size_t base = (((size_t)si << 8) + sj) * 16;
    float mx = -1e30f, sum;
    #pragma unroll
    for (int r = 0; r < 16; ++r){ so[r] = Ls[base+r] + b2s[r]; mx = fmaxf(mx, so[r]); }
    sum = 0.f;
    #pragma unroll
    for (int r = 0; r < 16; ++r){ so[r] = expf(so[r]-mx); sum += so[r]; }
    sum = 1.f/sum;
    #pragma unroll
    for (int r = 0; r < 16; ++r) so[r] *= sum;
    mx = -1e30f;
    #pragma unroll
    for (int r = 0; r < 16; ++r){
      dd[r] = Ldp[base+r] + Ldp[base+r+1048576] + Ldp[base+r+2097152] + b2d[r];
      mx = fmaxf(mx, dd[r]);
    }
    sum = 0.f;
    #pragma unroll
    for (int r = 0; r < 16; ++r){ dd[r] = expf(dd[r]-mx); sum += dd[r]; }
    sum = 1.f/sum;
    #pragma unroll
    for (int r = 0; r < 16; ++r) dd[r] *= sum;
  }
  const size_t ob = (size_t)p * 16;
  #pragma unroll
  for (int r = 0; r < 16; ++r){
    simo[ob+r] = so[r];
    divo[ob+r] = dd[r];
    Cb[ob+r]   = f2bf_s(0.5f*(so[r]+dd[r]));
  }
}

// ---------------------------------------------------------------------------
// T GEMM, BM=128, 256 thr, fused rel_w f32->bf16. Grid 384 (= 2 mt x 192 nt).
// ---------------------------------------------------------------------------
__global__ __launch_bounds__(256) void gemm_relT(
    const short* __restrict__ A,     // COMB, lda=1536
    const float* __restrict__ Bf,    // 12288 x 768 f32
    short* __restrict__ T,           // 256 x 12288 bf16
    const float* __restrict__ bias)  // 12288
{
  __shared__ short As[128*64];   // 16KB, 128B rows
  __shared__ short Bs[64*64];    // 8KB
  const int tid = threadIdx.x, lane = tid & 63, wv = tid >> 6;
  const int nt = blockIdx.x >> 1, mt = blockIdx.x & 1;
  const int n0 = nt*64, m0 = mt*128;
  const int wm = wv >> 1, wn = wv & 1;
  const int brow = tid >> 2, q4 = tid & 3;
  f32x4 acc[4][2] = {};
  for (int k0 = 0; k0 < 768; k0 += 64){
    if (k0) __syncthreads();
    #pragma unroll
    for (int q = 0; q < 4; ++q){
      const int d = (wv*4+q)*1024 + lane*16;
      const int row = d>>7, c = d&127;
      gload16((char*)As + (wv*4+q)*1024,
              (const char*)A + (size_t)(m0+row)*3072 + (size_t)k0*2 + (c ^ ((row&7)<<4)));
    }
    {
      const float* bp = Bf + (size_t)(n0+brow)*768 + k0 + q4*16;
      float4 v0 = *(const float4*)bp,      v1 = *(const float4*)(bp+4);
      float4 v2 = *(const float4*)(bp+8),  v3 = *(const float4*)(bp+12);
      union { uint4 v; unsigned u[4]; } ua, ub;
      ua.u[0]=pack2bf(v0.x,v0.y); ua.u[1]=pack2bf(v0.z,v0.w);
      ua.u[2]=pack2bf(v1.x,v1.y); ua.u[3]=pack2bf(v1.z,v1.w);
      ub.u[0]=pack2bf(v2.x,v2.y); ub.u[1]=pack2bf(v2.z,v2.w);
      ub.u[2]=pack2bf(v3.x,v3.y); ub.u[3]=pack2bf(v3.z,v3.w);
      const int bc = q4*32;
      *(uint4*)((char*)Bs + brow*128 + ((bc   ) ^ ((brow&7)<<4))) = ua.v;
      *(uint4*)((char*)Bs + brow*128 + ((bc+16) ^ ((brow&7)<<4))) = ub.v;
    }
    __syncthreads();
    #pragma unroll
    for (int kk = 0; kk < 2; ++kk){
      const int kb = kk*64 + (lane>>4)*16;
      s16x8 af[4], bfv[2];
      #pragma unroll
      for (int mi = 0; mi < 4; ++mi){
        const int row = wm*64 + mi*16 + (lane&15);
        af[mi] = *(const s16x8*)((char*)As + row*128 + (kb ^ ((row&7)<<4)));
      }
      #pragma unroll
      for (int ni = 0; ni < 2; ++ni){
        const int row = wn*32 + ni*16 + (lane&15);
        bfv[ni] = *(const s16x8*)((char*)Bs + row*128 + (kb ^ ((row&7)<<4)));
      }
      #pragma unroll
      for (int mi = 0; mi < 4; ++mi)
        #pragma unroll
        for (int ni = 0; ni < 2; ++ni)
          acc[mi][ni] = mfma16(af[mi], bfv[ni], acc[mi][ni]);
    }
  }
  #pragma unroll
  for (int mi = 0; mi < 4; ++mi)
    #pragma unroll
    for (int ni = 0; ni < 2; ++ni){
      const int nn = n0 + wn*32 + ni*16 + (lane&15);
      const float bv = bias[nn];
      #pragma unroll
      for (int r = 0; r < 4; ++r){
        const int row = m0 + wm*64 + mi*16 + (lane>>4)*4 + r;
        T[(size_t)row*12288 + nn] = f2bf_s(acc[mi][ni][r] + bv);
      }
    }
}

// ---------------------------------------------------------------------------
// LayerNorm(y + x) -> x (f32), comb[:, :768] (bf16), optional d_out x
// ---------------------------------------------------------------------------
__global__ __launch_bounds__(256) void ln_kernel(
    const float* __restrict__ y, float* __restrict__ x, short* __restrict__ combx,
    const float* __restrict__ g, const float* __restrict__ b, float* __restrict__ xfinal)
{
  const int row = blockIdx.x, tid = threadIdx.x;
  float tv[3]; float s = 0.f, s2 = 0.f;
  #pragma unroll
  for (int c = 0; c < 3; ++c){
    const int idx = tid + c*256;
    const float v = y[row*768+idx] + x[row*768+idx];
    tv[c] = v; s += v; s2 += v*v;
  }
  #pragma unroll
  for (int off = 32; off > 0; off >>= 1){ s += __shfl_down(s, off); s2 += __shfl_down(s2, off); }
  __shared__ float red[8];
  const int wid = tid >> 6, lane = tid & 63;
  if (lane == 0){ red[wid] = s; red[wid+4] = s2; }
  __syncthreads();
  if (tid == 0){
    red[0] = red[0]+red[1]+red[2]+red[3];
    red[4] = red[4]+red[5]+red[6]+red[7];
  }
  __syncthreads();
  const float mu = red[0]*(1.f/768.f);
  const float var = red[4]*(1.f/768.f) - mu*mu;
  const float inv = rsqrtf(var + 1e-5f);
  #pragma unroll
  for (int c = 0; c < 3; ++c){
    const int idx = tid + c*256;
    const float v = (tv[c]-mu)*inv*g[idx] + b[idx];
    x[row*768+idx] = v;
    combx[(size_t)row*1536 + idx] = f2bf_s(v);
    if (xfinal) xfinal[row*768+idx] = v;
  }
}

// ---------------------------------------------------------------------------
// setup_all: every f32->bf16 weight conversion + concat + bias concat
// ---------------------------------------------------------------------------
__device__ __forceinline__ void cvt4(const float* __restrict__ s,
                                     short* __restrict__ d, int i, int n){
  if (i >= n) return;
  float4 v = *(const float4*)(s+i);
  union { uint2 u; short s4[4]; } o;
  o.s4[0]=f2bf_s(v.x); o.s4[1]=f2bf_s(v.y); o.s4[2]=f2bf_s(v.z); o.s4[3]=f2bf_s(v.w);
  *(uint2*)(d+i) = o.u;
}

__global__ void setup_all(
    const float* __restrict__ sim_w2, const float* __restrict__ div_w2,
    const float* __restrict__ agg_w1, const float* __restrict__ agg_w2,
    const float* __restrict__ cls_w1, const float* __restrict__ sim_w1,
    const float* __restrict__ div_w1, const float* __restrict__ sup,
    const float* __restrict__ qry, const float* __restrict__ sim_b1,
    const float* __restrict__ div_b1,
    short* __restrict__ W2S, short* __restrict__ W2D, short* __restrict__ AW1,
    short* __restrict__ AW2, short* __restrict__ CW1, short* __restrict__ W1X4,
    float* __restrict__ XF, short* __restrict__ COMB, float* __restrict__ B1C)
{
  const int b = blockIdx.x, tid = threadIdx.x;
  if (b < 12)        cvt4(sim_w2, W2S, (b*256+tid)*4, 12288);
  else if (b < 24)   cvt4(div_w2, W2D, ((b-12)*256+tid)*4, 12288);
  else if (b < 3480) cvt4(agg_w1, AW1, ((b-24)*256+tid)*4, 3538944);
  else if (b < 5208) cvt4(agg_w2, AW2, ((b-3480)*256+tid)*4, 1769472);
  else if (b < 5496) cvt4(cls_w1, CW1, ((b-5208)*256+tid)*4, 294912);
  else if (b < 7800){                        // W1X4: {wa_s, wb_s, wa_d, wb_d}
    const int i = ((b-5496)*256+tid)*4;
    if (i < 2359296){
      const int mat = i / 589824, rem = i % 589824;
      const int r = rem / 768, c = rem % 768;
      const float* src = (mat < 2 ? sim_w1 : div_w1) + (size_t)r*1536 + (mat&1)*768 + c;
      float4 v = *(const float4*)src;
      union { uint2 u; short s4[4]; } o;
      o.s4[0]=f2bf_s(v.x); o.s4[1]=f2bf_s(v.y); o.s4[2]=f2bf_s(v.z); o.s4[3]=f2bf_s(v.w);
      *(uint2*)(W1X4+i) = o.u;
    }
  } else if (b < 7992){                      // concat x -> XF f32 + COMB bf16
    const int i = ((b-7800)*256+tid)*4;
    if (i < 196608){
      const int row = i / 768, col = i % 768;
      const float* s = (row < 128 ? sup + (size_t)row*768 : qry + (size_t)(row-128)*768) + col;
      float4 v = *(const float4*)s;
      *(float4*)(XF+i) = v;
      union { uint2 u; short s4[4]; } o;
      o.s4[0]=f2bf_s(v.x); o.s4[1]=f2bf_s(v.y); o.s4[2]=f2bf_s(v.z); o.s4[3]=f2bf_s(v.w);
      *(uint2*)(COMB + (size_t)row*1536 + col) = o.u;
    }
  } else {                                   // B1C = [b1s | 0 | b1d]
    for (int t = tid; t < 2304; t += 256)
      B1C[t] = (t < 768) ? sim_b1[t] : ((t < 1536) ? 0.f : div_b1[t-1536]);
  }
}

__global__ void cls2_kernel(const short* __restrict__ hc, const float* __restrict__ w2,
                            const float* __restrict__ b2, float* __restrict__ preds){
  const int t = blockIdx.x*192 + threadIdx.x;
  if (t >= 384) return;
  const int m = t/3, c = t - m*3;
  float s = b2[c];
  for (int k = 0; k < 384; ++k)
    s += bf_s2f(hc[m*384+k]) * w2[c*384+k];
  preds[m*3+c] = s;
}

// ---------------------------------------------------------------------------
// workspace layout (bytes, total ~52.7 MB)
// ---------------------------------------------------------------------------
static const size_t OFF_B1CAT = 0;          // 9216
static const size_t OFF_LS    = 16384;      // 4194304
static const size_t OFF_MSGF  = 4210688;    // 6291456  (8 slabs x 196608 f32)
static const size_t OFF_LDP   = 10502144;   // 12582912 (3 slabs)
static const size_t OFF_P     = 23085056;   // 2359296
static const size_t OFF_XF    = 25444352;   // 786432
static const size_t OFF_Y     = 26230784;   // 786432
static const size_t OFF_COMB  = 27017216;   // 786432
static const size_t OFF_CB    = 27803648;   // 2097152
static const size_t OFF_W1X4  = 29900800;   // 4718592
static const size_t OFF_W2S   = 34619392;   // 24576
static const size_t OFF_W2D   = 34643968;   // 24576
static const size_t OFF_AW1   = 34668544;   // 7077888
static const size_t OFF_AW2   = 41746432;   // 3538944
static const size_t OFF_CW1   = 45285376;   // 589824
static const size_t OFF_TBUF  = 45875200;   // 6291456
static const size_t OFF_HID1  = 52166656;   // 393216
static const size_t OFF_HIDC  = 52559872;   // 98304

extern "C" void kernel_launch(void* const* d_in, const int* in_sizes, int n_in,
                              void* d_out, int out_size, void* d_ws, size_t ws_size,
                              hipStream_t stream)
{
  (void)in_sizes; (void)n_in; (void)out_size; (void)ws_size;
  const float* sup    = (const float*)d_in[0];
  const float* qry    = (const float*)d_in[2];
  const float* sim_w1 = (const float*)d_in[3];
  const float* sim_b1 = (const float*)d_in[4];
  const float* sim_w2 = (const float*)d_in[5];
  const float* sim_b2 = (const float*)d_in[6];
  const float* div_w1 = (const float*)d_in[7];
  const float* div_b1 = (const float*)d_in[8];
  const float* div_w2 = (const float*)d_in[9];
  const float* div_b2 = (const float*)d_in[10];
  const float* rel_w  = (const float*)d_in[11];
  const float* rel_b  = (const float*)d_in[12];
  const float* agg_w1 = (const float*)d_in[13];
  const float* agg_b1 = (const float*)d_in[14];
  const float* agg_w2 = (const float*)d_in[15];
  const float* agg_b2 = (const float*)d_in[16];
  const float* ln_g   = (const float*)d_in[17];
  const float* ln_b   = (const float*)d_in[18];
  const float* cls_w1 = (const float*)d_in[19];
  const float* cls_b1 = (const float*)d_in[20];
  const float* cls_w2 = (const float*)d_in[21];
  const float* cls_b2 = (const float*)d_in[22];

  char* w = (char*)d_ws;
  float* B1C  = (float*)(w + OFF_B1CAT);
  float* LS   = (float*)(w + OFF_LS);
  float* MSGF = (float*)(w + OFF_MSGF);
  float* LDP  = (float*)(w + OFF_LDP);
  float* P2   = (float*)(w + OFF_P);
  float* XF   = (float*)(w + OFF_XF);
  float* Y    = (float*)(w + OFF_Y);
  short* COMB = (short*)(w + OFF_COMB);
  short* CB   = (short*)(w + OFF_CB);
  short* W1X4 = (short*)(w + OFF_W1X4);
  short* W2S  = (short*)(w + OFF_W2S);
  short* W2D  = (short*)(w + OFF_W2D);
  short* AW1  = (short*)(w + OFF_AW1);
  short* AW2  = (short*)(w + OFF_AW2);
  short* CW1  = (short*)(w + OFF_CW1);
  short* TBUF = (short*)(w + OFF_TBUF);
  short* HID1 = (short*)(w + OFF_HID1);
  short* HIDC = (short*)(w + OFF_HIDC);

  float* preds = (float*)d_out;
  float* simo  = preds + 384;
  float* divo  = simo + 1048576;
  float* xout  = divo + 1048576;

  // all setup in one kernel
  setup_all<<<7993, 256, 0, stream>>>(sim_w2, div_w2, agg_w1, agg_w2, cls_w1,
                                      sim_w1, div_w1, sup, qry, sim_b1, div_b1,
                                      W2S, W2D, AW1, AW2, CW1, W1X4, XF, COMB, B1C);

  // P2 = x @ [wa_s|wb_s|wa_d]^T + [b1s|0|b1d]   (M=256,N=2304,K=768)
  gemm_bt2<64,64,3><<<144, 256, 0, stream>>>(COMB, 1536, W1X4, 768, P2, nullptr, 2304,
                                             B1C, 768, 36);

  // relations
  pairrel4<<<dim3(288,3), 512, 0, stream>>>(COMB, W1X4 + (size_t)3*589824, P2, W2D, LDP);
  simpart<<<544, 256, 0, stream>>>(P2, W2S, LS);
  finisher2<<<256, 256, 0, stream>>>(LS, LDP, sim_b2, div_b2, simo, divo, CB);

  for (int l = 0; l < 3; ++l){
    gemm_relT<<<384, 256, 0, stream>>>(COMB, rel_w + (size_t)l*9437184, TBUF,
                                       rel_b + l*12288);
    gemm_msg<<<dim3(48,8), 256, 0, stream>>>(CB, TBUF, MSGF);
    msgsum<<<192, 256, 0, stream>>>(MSGF, COMB);
    gemm_bt2<32,32,2><<<192, 256, 0, stream>>>(COMB, 1536, AW1 + (size_t)l*1179648, 1536,
                                               nullptr, HID1, 768, agg_b1 + l*768, 1536, 24);
    gemm_bt2<32,32,3><<<192, 256, 0, stream>>>(HID1, 768, AW2 + (size_t)l*589824, 768,
                                               Y, nullptr, 768, agg_b2 + l*768, 768, 24);
    ln_kernel<<<256, 256, 0, stream>>>(Y, XF, COMB, ln_g + l*768, ln_b + l*768,
                                       (l == 2) ? xout : nullptr);
  }

  gemm_bt2<32,32,2><<<48, 256, 0, stream>>>(COMB + (size_t)128*1536, 1536, CW1, 768,
                                            nullptr, HIDC, 384, cls_b1, 768, 12);
  cls2_kernel<<<2, 192, 0, stream>>>(HIDC, cls_w2, cls_b2, preds);
}